// Round 2
// baseline (341.951 us; speedup 1.0000x reference)
//
#include <hip/hip_runtime.h>
#include <math.h>

#define NH 16
#define TT 1024
#define HD 64

// Generic fp32 GEMM: C = A[M,K] @ B[K,N]. 64x64 tile, 256 threads, 4x4 microtile.
// MODE 0: plain row-major C write. MODE 1: qkv scatter into q/k/v [h][t][d] buffers.
template<int MODE>
__global__ __launch_bounds__(256) void gemm_f32(const float* __restrict__ A,
                                                const float* __restrict__ B,
                                                float* __restrict__ C,
                                                int M, int N, int K) {
  __shared__ float As[16][65];   // [k][m], padded
  __shared__ float Bs[16][64];   // [k][n]
  const int tid = threadIdx.x;
  const int tx = tid & 15, ty = tid >> 4;
  const int row0 = blockIdx.y * 64;
  const int col0 = blockIdx.x * 64;
  float acc[4][4] = {{0.f, 0.f, 0.f, 0.f}};
  for (int k0 = 0; k0 < K; k0 += 16) {
#pragma unroll
    for (int i = 0; i < 4; ++i) {
      int e = tid + 256 * i;
      int ma = e >> 4, ka = e & 15;
      As[ka][ma] = A[(size_t)(row0 + ma) * K + k0 + ka];
      int kb = e >> 6, nb = e & 63;
      Bs[kb][nb] = B[(size_t)(k0 + kb) * N + col0 + nb];
    }
    __syncthreads();
#pragma unroll
    for (int kk = 0; kk < 16; ++kk) {
      float a[4], b[4];
#pragma unroll
      for (int i = 0; i < 4; ++i) a[i] = As[kk][ty * 4 + i];
#pragma unroll
      for (int j = 0; j < 4; ++j) b[j] = Bs[kk][tx * 4 + j];
#pragma unroll
      for (int i = 0; i < 4; ++i)
#pragma unroll
        for (int j = 0; j < 4; ++j) acc[i][j] = fmaf(a[i], b[j], acc[i][j]);
    }
    __syncthreads();
  }
#pragma unroll
  for (int i = 0; i < 4; ++i) {
    int t = row0 + ty * 4 + i;
#pragma unroll
    for (int j = 0; j < 4; ++j) {
      int n = col0 + tx * 4 + j;
      if (MODE == 0) {
        C[(size_t)t * N + n] = acc[i][j];
      } else {
        // n in [0,3072): which (q/k/v), head, dim. Store [which][h][t][d].
        int which = n >> 10;
        int within = n & 1023;
        int h = within >> 6;
        int d = within & 63;
        C[(size_t)which * (NH * TT * HD) + (size_t)h * (TT * HD) + t * HD + d] = acc[i][j];
      }
    }
  }
}

// One block per (t, h). 128 threads. Threads 0..D-1: score for one neighbor.
// LDS tree softmax over <=128 entries, then lanes 0..63 do the PV accumulation.
__global__ __launch_bounds__(128) void attn_kernel(const float* __restrict__ q,
                                                   const float* __restrict__ k,
                                                   const float* __restrict__ v,
                                                   const int* __restrict__ nidx,
                                                   float* __restrict__ y, int D) {
  const int t = blockIdx.x;
  const int h = blockIdx.y;
  const int tid = threadIdx.x;
  __shared__ float qs[HD];
  __shared__ float w[128];
  __shared__ int js[128];
  __shared__ float red[128];
  const float* kh = k + (size_t)h * TT * HD;
  const float* vh = v + (size_t)h * TT * HD;
  if (tid < HD) qs[tid] = q[(size_t)h * TT * HD + (size_t)t * HD + tid];
  int j = -1;
  if (tid < D) {
    int jj = nidx[((size_t)h * TT + t) * D + tid];
    if (jj >= 0 && jj <= t) j = jj;   // valid & causal
  }
  js[tid] = j;
  __syncthreads();

  float s = -INFINITY;
  if (j >= 0) {
    const float* kr = kh + (size_t)j * HD;
    float acc = 0.f;
#pragma unroll
    for (int d = 0; d < HD; ++d) acc = fmaf(qs[d], kr[d], acc);
    s = acc * 0.125f;   // 1/sqrt(64)
  }
  red[tid] = s;
  __syncthreads();
#pragma unroll
  for (int off = 64; off > 0; off >>= 1) {
    if (tid < off) red[tid] = fmaxf(red[tid], red[tid + off]);
    __syncthreads();
  }
  float m = red[0];
  __syncthreads();
  float e = (j >= 0) ? expf(s - m) : 0.f;
  red[tid] = e;
  __syncthreads();
#pragma unroll
  for (int off = 64; off > 0; off >>= 1) {
    if (tid < off) red[tid] += red[tid + off];
    __syncthreads();
  }
  float denom = red[0];
  w[tid] = e / denom;
  __syncthreads();

  if (tid < HD) {
    float acc = 0.f;
    for (int n = 0; n < D; ++n) {
      int jn = js[n];
      if (jn >= 0) acc = fmaf(w[n], vh[(size_t)jn * HD + tid], acc);
    }
    // y laid out [t][h*64+d] so the output GEMM is a plain row-major GEMM
    y[(size_t)t * (NH * HD) + h * HD + tid] = acc;
  }
}

extern "C" void kernel_launch(void* const* d_in, const int* in_sizes, int n_in,
                              void* d_out, int out_size, void* d_ws, size_t ws_size,
                              hipStream_t stream) {
  const float* x    = (const float*)d_in[0];
  const float* Wqkv = (const float*)d_in[1];
  const float* Wout = (const float*)d_in[2];
  const int*   nidx = (const int*)d_in[3];
  float* out = (float*)d_out;
  float* ws  = (float*)d_ws;

  float* q  = ws;                              // [16][1024][64] = 1M floats
  float* kk = ws + (size_t)NH * TT * HD;       // 1M floats
  float* vv = ws + 2 * (size_t)NH * TT * HD;   // 1M floats
  float* y  = ws + 3 * (size_t)NH * TT * HD;   // [1024][1024] = 1M floats

  int D = in_sizes[3] / (NH * TT);             // 83 by construction

  // qkv = x @ Wqkv, scattered into q/k/v [h][t][d]
  gemm_f32<1><<<dim3(3 * 1024 / 64, TT / 64), 256, 0, stream>>>(x, Wqkv, q, TT, 3 * 1024, 1024);
  // gathered masked-softmax attention
  attn_kernel<<<dim3(TT, NH), 128, 0, stream>>>(q, kk, vv, nidx, y, D);
  // out = y @ Wout
  gemm_f32<0><<<dim3(1024 / 64, TT / 64), 256, 0, stream>>>(y, Wout, out, TT, 1024, 1024);
}

// Round 3
// 99.875 us; speedup vs baseline: 3.4238x; 3.4238x over previous
//
#include <hip/hip_runtime.h>
#include <math.h>

#define NH 16
#define TT 1024
#define HD 64
#define NE 1024

typedef unsigned int u32;
typedef unsigned short u16;
typedef __bf16 bf16x8 __attribute__((ext_vector_type(8)));
typedef float f32x4 __attribute__((ext_vector_type(4)));

__device__ inline u16 f2bf(float f) {
  u32 u = __builtin_bit_cast(u32, f);
  u32 r = (u + 0x7fffu + ((u >> 16) & 1u)) >> 16;
  return (u16)r;
}
__device__ inline float bf2f(u16 h) {
  return __builtin_bit_cast(float, (u32)h << 16);
}
__device__ inline void gload16(const void* g, void* l) {
  __builtin_amdgcn_global_load_lds((const __attribute__((address_space(1))) void*)g,
                                   (__attribute__((address_space(3))) void*)l, 16, 0, 0);
}

// fp32 -> bf16 elementwise, 4 elems/thread
__global__ __launch_bounds__(256) void f32_to_bf16(const float* __restrict__ in,
                                                   u16* __restrict__ out) {
  int i = blockIdx.x * 256 + threadIdx.x;
  float4 f = ((const float4*)in)[i];
  u16 o0 = f2bf(f.x), o1 = f2bf(f.y), o2 = f2bf(f.z), o3 = f2bf(f.w);
  ushort4 o = {o0, o1, o2, o3};
  ((ushort4*)out)[i] = o;
}

// W[K][N] fp32 -> WT[N][K] bf16, 64x64 LDS tile transpose
__global__ __launch_bounds__(256) void transpose_to_bf16(const float* __restrict__ W,
                                                         u16* __restrict__ WT,
                                                         int K, int N) {
  __shared__ float tile[64][65];
  const int n0 = blockIdx.x * 64, k0 = blockIdx.y * 64;
  const int tid = threadIdx.x;
#pragma unroll
  for (int it = 0; it < 16; ++it) {
    int idx = it * 256 + tid;
    int r = idx >> 6, c = idx & 63;
    tile[r][c] = W[(size_t)(k0 + r) * N + n0 + c];
  }
  __syncthreads();
#pragma unroll
  for (int it = 0; it < 16; ++it) {
    int idx = it * 256 + tid;
    int nn = idx >> 6, kk = idx & 63;
    WT[(size_t)(n0 + nn) * K + k0 + kk] = f2bf(tile[kk][nn]);
  }
}

// bf16 MFMA GEMM, m97 structure: 128x128 tile, BK=64, 4 waves (2x2), 64x64/wave.
// A[M][K] bf16 row-major, Bt[N][K] bf16 row-major (= B^T).
// MODE 0: C = float*, plain [M][N] write. MODE 1: C = u16*, qkv scatter.
template<int MODE>
__global__ __launch_bounds__(256) void gemm_bf16(const u16* __restrict__ A,
                                                 const u16* __restrict__ Bt,
                                                 void* __restrict__ Cv,
                                                 int M, int N, int K) {
  __shared__ u16 As[128 * 64];
  __shared__ u16 Bs[128 * 64];
  const int tid = threadIdx.x;
  const int lane = tid & 63;
  const int wv = tid >> 6;
  const int wm = wv >> 1, wn = wv & 1;
  const int row0 = blockIdx.y * 128;
  const int col0 = blockIdx.x * 128;

  f32x4 acc[4][4] = {};

  for (int k0 = 0; k0 < K; k0 += 64) {
#pragma unroll
    for (int it = 0; it < 4; ++it) {
      int idx = it * 256 + tid;
      int r = idx >> 3;            // 0..127
      int ke = (idx & 7) * 8;      // 0..56
      gload16(A + (size_t)(row0 + r) * K + k0 + ke, As + idx * 8);
      gload16(Bt + (size_t)(col0 + r) * K + k0 + ke, Bs + idx * 8);
    }
    __syncthreads();
#pragma unroll
    for (int kk = 0; kk < 64; kk += 32) {
      bf16x8 af[4], bfr[4];
#pragma unroll
      for (int mi = 0; mi < 4; ++mi)
        af[mi] = *(const bf16x8*)&As[(wm * 64 + mi * 16 + (lane & 15)) * 64 + kk + (lane >> 4) * 8];
#pragma unroll
      for (int ni = 0; ni < 4; ++ni)
        bfr[ni] = *(const bf16x8*)&Bs[(wn * 64 + ni * 16 + (lane & 15)) * 64 + kk + (lane >> 4) * 8];
#pragma unroll
      for (int mi = 0; mi < 4; ++mi)
#pragma unroll
        for (int ni = 0; ni < 4; ++ni)
          acc[mi][ni] = __builtin_amdgcn_mfma_f32_16x16x32_bf16(af[mi], bfr[ni], acc[mi][ni], 0, 0, 0);
    }
    __syncthreads();
  }

  const int rbase = row0 + wm * 64 + (lane >> 4) * 4;
  const int cbase = col0 + wn * 64 + (lane & 15);
#pragma unroll
  for (int mi = 0; mi < 4; ++mi) {
#pragma unroll
    for (int ni = 0; ni < 4; ++ni) {
      int n = cbase + ni * 16;
#pragma unroll
      for (int r = 0; r < 4; ++r) {
        int t = rbase + mi * 16 + r;
        float val = acc[mi][ni][r];
        if (MODE == 0) {
          ((float*)Cv)[(size_t)t * N + n] = val;
        } else {
          int which = n >> 10, within = n & 1023;
          int h = within >> 6, d = within & 63;
          ((u16*)Cv)[(size_t)which * (NH * TT * HD) + (size_t)h * (TT * HD) +
                     (size_t)t * HD + d] = f2bf(val);
        }
      }
    }
  }
}

// One wave per (t,h). 4 waves/block, no block barriers (wave-internal LDS only).
__global__ __launch_bounds__(256) void attn2(const u16* __restrict__ qkv,
                                             const int* __restrict__ nidx,
                                             u16* __restrict__ y, int D) {
  __shared__ float qs[4][HD];
  __shared__ float wl[4][128];
  __shared__ int js[4][128];
  const int tid = threadIdx.x;
  const int lane = tid & 63;
  const int wv = tid >> 6;
  const int wid = blockIdx.x * 4 + wv;
  const int h = wid >> 10;
  const int t = wid & 1023;

  const u16* q = qkv;
  const u16* k = qkv + (size_t)NH * TT * HD;
  const u16* v = qkv + 2 * (size_t)NH * TT * HD;

  qs[wv][lane] = bf2f(q[((size_t)h * TT + t) * HD + lane]);
  asm volatile("s_waitcnt lgkmcnt(0)" ::: "memory");

  const int* nrow = nidx + ((size_t)h * TT + t) * D;
  float s[2];
  int jj[2];
#pragma unroll
  for (int sl = 0; sl < 2; ++sl) {
    int n = lane + sl * 64;
    int j = -1;
    if (n < D) {
      int cand = nrow[n];
      if (cand >= 0 && cand <= t) j = cand;
    }
    jj[sl] = j;
    js[wv][n] = j;
    float acc = 0.f;
    if (j >= 0) {
      const uint4* kr4 = (const uint4*)(k + ((size_t)h * TT + j) * HD);
#pragma unroll
      for (int q4 = 0; q4 < 8; ++q4) {
        uint4 uu = kr4[q4];
        const u32 us[4] = {uu.x, uu.y, uu.z, uu.w};
#pragma unroll
        for (int e = 0; e < 4; ++e) {
          int d = q4 * 8 + e * 2;
          acc = fmaf(qs[wv][d],     __builtin_bit_cast(float, us[e] << 16),
                fmaf(qs[wv][d + 1], __builtin_bit_cast(float, us[e] & 0xffff0000u), acc));
        }
      }
    }
    s[sl] = (j >= 0) ? acc * 0.125f : -INFINITY;
  }

  float m = fmaxf(s[0], s[1]);
#pragma unroll
  for (int off = 32; off > 0; off >>= 1) m = fmaxf(m, __shfl_xor(m, off, 64));
  float e0 = (jj[0] >= 0) ? __expf(s[0] - m) : 0.f;
  float e1 = (jj[1] >= 0) ? __expf(s[1] - m) : 0.f;
  float sum = e0 + e1;
#pragma unroll
  for (int off = 32; off > 0; off >>= 1) sum += __shfl_xor(sum, off, 64);
  float inv = 1.f / sum;
  wl[wv][lane] = e0 * inv;
  wl[wv][lane + 64] = e1 * inv;
  asm volatile("s_waitcnt lgkmcnt(0)" ::: "memory");

  // PV: lane = d. w is 0 for masked slots, so branchless with clamped index.
  float acc = 0.f;
  const u16* vh = v + (size_t)h * TT * HD;
  for (int n = 0; n < D; ++n) {
    int j = js[wv][n];
    j = j >= 0 ? j : 0;
    acc = fmaf(wl[wv][n], bf2f(vh[(size_t)j * HD + lane]), acc);
  }
  y[(size_t)t * NE + h * HD + lane] = f2bf(acc);
}

extern "C" void kernel_launch(void* const* d_in, const int* in_sizes, int n_in,
                              void* d_out, int out_size, void* d_ws, size_t ws_size,
                              hipStream_t stream) {
  const float* x    = (const float*)d_in[0];
  const float* Wqkv = (const float*)d_in[1];
  const float* Wout = (const float*)d_in[2];
  const int*   nidx = (const int*)d_in[3];
  float* out = (float*)d_out;

  u16* ws16  = (u16*)d_ws;
  u16* xb    = ws16;                 // 1M u16 (2MB)  -- also reused as y after GEMM1
  u16* WqkvT = ws16 + 1048576;       // 3M u16 (6MB)
  u16* WoutT = ws16 + 4194304;       // 1M u16 (2MB)
  u16* qkvb  = ws16 + 5242880;       // 3M u16 (6MB)

  const int D = in_sizes[3] / (NH * TT);   // 83

  f32_to_bf16<<<1024, 256, 0, stream>>>(x, xb);
  transpose_to_bf16<<<dim3(48, 16), 256, 0, stream>>>(Wqkv, WqkvT, NE, 3 * NE);
  transpose_to_bf16<<<dim3(16, 16), 256, 0, stream>>>(Wout, WoutT, NE, NE);

  // qkv = x @ Wqkv  (scatter epilogue into [which][h][t][d] bf16)
  gemm_bf16<1><<<dim3(24, 8), 256, 0, stream>>>(xb, WqkvT, qkvb, TT, 3 * NE, NE);
  // gathered masked-softmax attention, y (bf16) overlays xb
  attn2<<<TT * NH / 4, 256, 0, stream>>>(qkvb, nidx, xb, D);
  // out = y @ Wout (fp32 write to d_out)
  gemm_bf16<0><<<dim3(8, 8), 256, 0, stream>>>(xb, WoutT, out, TT, NE, NE);
}

// Round 4
// 99.440 us; speedup vs baseline: 3.4388x; 1.0044x over previous
//
#include <hip/hip_runtime.h>
#include <math.h>

#define NH 16
#define TT 1024
#define HD 64
#define NE 1024

typedef unsigned int u32;
typedef unsigned short u16;
typedef __bf16 bf16x8 __attribute__((ext_vector_type(8)));
typedef float f32x4 __attribute__((ext_vector_type(4)));

__device__ inline u16 f2bf(float f) {
  u32 u = __builtin_bit_cast(u32, f);
  u32 r = (u + 0x7fffu + ((u >> 16) & 1u)) >> 16;
  return (u16)r;
}
__device__ inline float bf2f(u16 h) {
  return __builtin_bit_cast(float, (u32)h << 16);
}
__device__ inline void gload16(const void* g, void* l) {
  __builtin_amdgcn_global_load_lds((const __attribute__((address_space(1))) void*)g,
                                   (__attribute__((address_space(3))) void*)l, 16, 0, 0);
}

// fp32 -> bf16 elementwise, 4 elems/thread
__global__ __launch_bounds__(256) void f32_to_bf16(const float* __restrict__ in,
                                                   u16* __restrict__ out) {
  int i = blockIdx.x * 256 + threadIdx.x;
  float4 f = ((const float4*)in)[i];
  ushort4 o = {f2bf(f.x), f2bf(f.y), f2bf(f.z), f2bf(f.w)};
  ((ushort4*)out)[i] = o;
}

// Fused transpose: W[K][N] fp32 -> WT[N][K] bf16 for both Wqkv and Wout.
__global__ __launch_bounds__(256) void transpose_both(const float* __restrict__ Wqkv,
                                                      const float* __restrict__ Wout,
                                                      u16* __restrict__ WqkvT,
                                                      u16* __restrict__ WoutT) {
  __shared__ float tile[64][65];
  const int bx = blockIdx.x;
  const float* W;
  u16* WT;
  int N, n0;
  if (bx < 48) { W = Wqkv; WT = WqkvT; N = 3 * NE; n0 = bx * 64; }
  else         { W = Wout; WT = WoutT; N = NE;     n0 = (bx - 48) * 64; }
  const int k0 = blockIdx.y * 64;
  const int tid = threadIdx.x;
#pragma unroll
  for (int it = 0; it < 16; ++it) {
    int idx = it * 256 + tid;
    int r = idx >> 6, c = idx & 63;
    tile[r][c] = W[(size_t)(k0 + r) * N + n0 + c];
  }
  __syncthreads();
#pragma unroll
  for (int it = 0; it < 16; ++it) {
    int idx = it * 256 + tid;
    int nn = idx >> 6, kk = idx & 63;
    WT[(size_t)(n0 + nn) * NE + k0 + kk] = f2bf(tile[kk][nn]);
  }
}

// Source-swizzled staging: LDS slot (r,kg) gets global k-chunk kg^(r&7).
// Read of chunk c at row r -> slot c^(r&7) (involution), spreading the 16
// same-column rows of a ds_read_b128 across 8 distinct 16B bank groups.
__device__ __forceinline__ void stage_tile(const u16* __restrict__ G, int ldk,
                                           u16* L, int tid) {
#pragma unroll
  for (int it = 0; it < 4; ++it) {
    int idx = it * 256 + tid;
    int r = idx >> 3, kg = idx & 7;
    int kgs = kg ^ (r & 7);
    gload16(G + (size_t)r * ldk + (kgs << 3), L + (idx << 3));
  }
}

// bf16 MFMA GEMM: 128x128 tile, BK=64, 4 waves (2x2), 64x64/wave,
// double-buffered LDS with 2-phase prefetch (stage next before compute cur).
// A[M][K] bf16, Bt[N][K] bf16 (= B^T).
// MODE 0: f32 split-K partial write to ((float*)Cv)+sk*M*N. MODE 1: qkv scatter (SPLITK must be 1).
template<int MODE, int SPLITK>
__global__ __launch_bounds__(256) void gemm128(const u16* __restrict__ A,
                                               const u16* __restrict__ Bt,
                                               void* __restrict__ Cv,
                                               int M, int N, int K) {
  __shared__ u16 As[2][128 * 64];
  __shared__ u16 Bs[2][128 * 64];
  const int tid = threadIdx.x;
  const int lane = tid & 63;
  const int wv = tid >> 6;
  const int wm = wv >> 1, wn = wv & 1;
  const int row0 = blockIdx.y * 128;
  const int col0 = blockIdx.x * 128;
  const int sk = blockIdx.z;
  const int Klen = K / SPLITK;
  const int k0 = sk * Klen;
  const int nsteps = Klen >> 6;

  const u16* Ab = A + (size_t)row0 * K + k0;
  const u16* Bb = Bt + (size_t)col0 * K + k0;

  f32x4 acc[4][4] = {};

  stage_tile(Ab, K, As[0], tid);
  stage_tile(Bb, K, Bs[0], tid);
  __syncthreads();

  int buf = 0;
  for (int ks = 0; ks < nsteps; ++ks) {
    if (ks + 1 < nsteps) {
      stage_tile(Ab + (ks + 1) * 64, K, As[buf ^ 1], tid);
      stage_tile(Bb + (ks + 1) * 64, K, Bs[buf ^ 1], tid);
    }
#pragma unroll
    for (int half = 0; half < 2; ++half) {
      const int kk = half * 32;
      bf16x8 af[4], bfr[4];
#pragma unroll
      for (int mi = 0; mi < 4; ++mi) {
        int r = wm * 64 + mi * 16 + (lane & 15);
        int c = (kk >> 3) + (lane >> 4);
        int slot = c ^ (r & 7);
        af[mi] = *(const bf16x8*)&As[buf][(r * 8 + slot) * 8];
      }
#pragma unroll
      for (int ni = 0; ni < 4; ++ni) {
        int r = wn * 64 + ni * 16 + (lane & 15);
        int c = (kk >> 3) + (lane >> 4);
        int slot = c ^ (r & 7);
        bfr[ni] = *(const bf16x8*)&Bs[buf][(r * 8 + slot) * 8];
      }
#pragma unroll
      for (int mi = 0; mi < 4; ++mi)
#pragma unroll
        for (int ni = 0; ni < 4; ++ni)
          acc[mi][ni] = __builtin_amdgcn_mfma_f32_16x16x32_bf16(af[mi], bfr[ni], acc[mi][ni], 0, 0, 0);
    }
    __syncthreads();
    buf ^= 1;
  }

  const int rbase = row0 + wm * 64 + (lane >> 4) * 4;
  const int cbase = col0 + wn * 64 + (lane & 15);
#pragma unroll
  for (int mi = 0; mi < 4; ++mi) {
#pragma unroll
    for (int ni = 0; ni < 4; ++ni) {
      int n = cbase + ni * 16;
#pragma unroll
      for (int r = 0; r < 4; ++r) {
        int t = rbase + mi * 16 + r;
        float val = acc[mi][ni][r];
        if (MODE == 0) {
          ((float*)Cv)[(size_t)sk * M * N + (size_t)t * N + n] = val;
        } else {
          int which = n >> 10, within = n & 1023;
          int h = within >> 6, d = within & 63;
          ((u16*)Cv)[(size_t)which * (NH * TT * HD) + (size_t)h * (TT * HD) +
                     (size_t)t * HD + d] = f2bf(val);
        }
      }
    }
  }
}

__global__ __launch_bounds__(256) void reduce_out(const float* __restrict__ P,
                                                  float* __restrict__ out) {
  int i = blockIdx.x * 256 + threadIdx.x;
  f32x4 a = ((const f32x4*)P)[i];
  a += ((const f32x4*)(P + (size_t)TT * NE))[i];
  a += ((const f32x4*)(P + 2 * (size_t)TT * NE))[i];
  a += ((const f32x4*)(P + 3 * (size_t)TT * NE))[i];
  ((f32x4*)out)[i] = a;
}

// One wave per (t,h). 4 waves/block, wave-internal LDS only.
template<int DD>
__global__ __launch_bounds__(256) void attn2(const u16* __restrict__ qkv,
                                             const int* __restrict__ nidx,
                                             u16* __restrict__ y, int Drt) {
  const int D = (DD > 0) ? DD : Drt;
  __shared__ float qs[4][HD];
  __shared__ float wl[4][128];
  __shared__ int js[4][128];
  const int tid = threadIdx.x;
  const int lane = tid & 63;
  const int wv = tid >> 6;
  const int wid = blockIdx.x * 4 + wv;
  const int h = wid >> 10;
  const int t = wid & 1023;

  const u16* q = qkv;
  const u16* k = qkv + (size_t)NH * TT * HD;
  const u16* v = qkv + 2 * (size_t)NH * TT * HD;

  qs[wv][lane] = bf2f(q[((size_t)h * TT + t) * HD + lane]);
  asm volatile("s_waitcnt lgkmcnt(0)" ::: "memory");

  const int* nrow = nidx + ((size_t)h * TT + t) * D;
  float s[2];
  int jj[2];
#pragma unroll
  for (int sl = 0; sl < 2; ++sl) {
    int n = lane + sl * 64;
    int j = -1;
    if (n < D) {
      int cand = nrow[n];
      if (cand >= 0 && cand <= t) j = cand;
    }
    jj[sl] = j;
    js[wv][n] = j;
    float a0 = 0.f, a1 = 0.f, a2 = 0.f, a3 = 0.f;
    if (j >= 0) {
      const uint4* kr4 = (const uint4*)(k + ((size_t)h * TT + j) * HD);
#pragma unroll
      for (int q4 = 0; q4 < 8; ++q4) {
        uint4 uu = kr4[q4];
        const u32 us[4] = {uu.x, uu.y, uu.z, uu.w};
        float part = 0.f;
#pragma unroll
        for (int e = 0; e < 4; ++e) {
          int d = q4 * 8 + e * 2;
          part = fmaf(qs[wv][d],     __builtin_bit_cast(float, us[e] << 16),
                 fmaf(qs[wv][d + 1], __builtin_bit_cast(float, us[e] & 0xffff0000u), part));
        }
        if ((q4 & 3) == 0) a0 += part; else if ((q4 & 3) == 1) a1 += part;
        else if ((q4 & 3) == 2) a2 += part; else a3 += part;
      }
    }
    float acc = (a0 + a1) + (a2 + a3);
    s[sl] = (j >= 0) ? acc * 0.125f : -INFINITY;
  }

  float m = fmaxf(s[0], s[1]);
#pragma unroll
  for (int off = 32; off > 0; off >>= 1) m = fmaxf(m, __shfl_xor(m, off, 64));
  float e0 = (jj[0] >= 0) ? __expf(s[0] - m) : 0.f;
  float e1 = (jj[1] >= 0) ? __expf(s[1] - m) : 0.f;
  float sum = e0 + e1;
#pragma unroll
  for (int off = 32; off > 0; off >>= 1) sum += __shfl_xor(sum, off, 64);
  float inv = 1.f / sum;
  wl[wv][lane] = e0 * inv;
  wl[wv][lane + 64] = e1 * inv;
  asm volatile("s_waitcnt lgkmcnt(0)" ::: "memory");

  float acc = 0.f;
  const u16* vh = v + (size_t)h * TT * HD;
#pragma unroll 8
  for (int n = 0; n < D; ++n) {
    int j = js[wv][n];
    j = j >= 0 ? j : 0;
    acc = fmaf(wl[wv][n], bf2f(vh[(size_t)j * HD + lane]), acc);
  }
  y[(size_t)t * NE + h * HD + lane] = f2bf(acc);
}

extern "C" void kernel_launch(void* const* d_in, const int* in_sizes, int n_in,
                              void* d_out, int out_size, void* d_ws, size_t ws_size,
                              hipStream_t stream) {
  const float* x    = (const float*)d_in[0];
  const float* Wqkv = (const float*)d_in[1];
  const float* Wout = (const float*)d_in[2];
  const int*   nidx = (const int*)d_in[3];
  float* out = (float*)d_out;

  u16* ws16  = (u16*)d_ws;
  u16* xb    = ws16;                 // 1M u16 (2MB); reused as y after gemm1
  u16* WqkvT = ws16 + 1048576;       // 3M u16 (6MB)
  u16* WoutT = ws16 + 4194304;       // 1M u16 (2MB)
  u16* qkvb  = ws16 + 5242880;       // 3M u16 (6MB)
  float* Pout = (float*)((char*)d_ws + (32u << 20));  // 4 x 4MB f32 partials

  const int D = in_sizes[3] / (NH * TT);   // 83

  f32_to_bf16<<<1024, 256, 0, stream>>>(x, xb);
  transpose_both<<<dim3(64, 16), 256, 0, stream>>>(Wqkv, Wout, WqkvT, WoutT);

  // qkv = x @ Wqkv  (scatter epilogue into [which][h][t][d] bf16)
  gemm128<1, 1><<<dim3(24, 8, 1), 256, 0, stream>>>(xb, WqkvT, qkvb, TT, 3 * NE, NE);

  // attention; y (bf16) overlays xb
  if (D == 83) attn2<83><<<TT * NH / 4, 256, 0, stream>>>(qkvb, nidx, xb, D);
  else         attn2<0><<<TT * NH / 4, 256, 0, stream>>>(qkvb, nidx, xb, D);

  // out = y @ Wout, split-K=4 partials then reduce
  gemm128<0, 4><<<dim3(8, 8, 4), 256, 0, stream>>>(xb, WoutT, Pout, TT, NE, NE);
  reduce_out<<<TT * NE / 4 / 256, 256, 0, stream>>>(Pout, out);
}

// Round 5
// 66.635 us; speedup vs baseline: 5.1317x; 1.4923x over previous
//
#include <hip/hip_runtime.h>
#include <math.h>

#define NH 16
#define TT 1024
#define HD 64
#define NE 1024

typedef unsigned int u32;
typedef unsigned short u16;
typedef __bf16 bf16x8 __attribute__((ext_vector_type(8)));
typedef float f32x4 __attribute__((ext_vector_type(4)));

__device__ inline u16 f2bf(float f) {
  u32 u = __builtin_bit_cast(u32, f);
  u32 r = (u + 0x7fffu + ((u >> 16) & 1u)) >> 16;
  return (u16)r;
}
__device__ inline float bf2f(u16 h) {
  return __builtin_bit_cast(float, (u32)h << 16);
}
__device__ inline void gload16(const void* g, void* l) {
  __builtin_amdgcn_global_load_lds((const __attribute__((address_space(1))) void*)g,
                                   (__attribute__((address_space(3))) void*)l, 16, 0, 0);
}

// fp32 -> bf16 elementwise, 4 elems/thread
__global__ __launch_bounds__(256) void f32_to_bf16(const float* __restrict__ in,
                                                   u16* __restrict__ out) {
  int i = blockIdx.x * 256 + threadIdx.x;
  float4 f = ((const float4*)in)[i];
  ushort4 o = {f2bf(f.x), f2bf(f.y), f2bf(f.z), f2bf(f.w)};
  ((ushort4*)out)[i] = o;
}

// Fused transpose: W[K][N] fp32 -> WT[N][K] bf16 for both Wqkv and Wout.
__global__ __launch_bounds__(256) void transpose_both(const float* __restrict__ Wqkv,
                                                      const float* __restrict__ Wout,
                                                      u16* __restrict__ WqkvT,
                                                      u16* __restrict__ WoutT) {
  __shared__ float tile[64][65];
  const int bx = blockIdx.x;
  const float* W;
  u16* WT;
  int N, n0;
  if (bx < 48) { W = Wqkv; WT = WqkvT; N = 3 * NE; n0 = bx * 64; }
  else         { W = Wout; WT = WoutT; N = NE;     n0 = (bx - 48) * 64; }
  const int k0 = blockIdx.y * 64;
  const int tid = threadIdx.x;
#pragma unroll
  for (int it = 0; it < 16; ++it) {
    int idx = it * 256 + tid;
    int r = idx >> 6, c = idx & 63;
    tile[r][c] = W[(size_t)(k0 + r) * N + n0 + c];
  }
  __syncthreads();
#pragma unroll
  for (int it = 0; it < 16; ++it) {
    int idx = it * 256 + tid;
    int nn = idx >> 6, kk = idx & 63;
    WT[(size_t)(n0 + nn) * NE + k0 + kk] = f2bf(tile[kk][nn]);
  }
}

// Source-swizzled staging: LDS slot (r,kg) gets global k-chunk kg^(r&7).
__device__ __forceinline__ void stage_tile(const u16* __restrict__ G, int ldk,
                                           u16* L, int tid) {
#pragma unroll
  for (int it = 0; it < 4; ++it) {
    int idx = it * 256 + tid;
    int r = idx >> 3, kg = idx & 7;
    int kgs = kg ^ (r & 7);
    gload16(G + (size_t)r * ldk + (kgs << 3), L + (idx << 3));
  }
}

// bf16 MFMA GEMM: 128x128 tile, BK=64, 4 waves (2x2), dbuf + swizzled LDS.
// MODE 0: f32 split-K partial write. MODE 1: qkv scatter (SPLITK==1).
template<int MODE, int SPLITK>
__global__ __launch_bounds__(256) void gemm128(const u16* __restrict__ A,
                                               const u16* __restrict__ Bt,
                                               void* __restrict__ Cv,
                                               int M, int N, int K) {
  __shared__ u16 As[2][128 * 64];
  __shared__ u16 Bs[2][128 * 64];
  const int tid = threadIdx.x;
  const int lane = tid & 63;
  const int wv = tid >> 6;
  const int wm = wv >> 1, wn = wv & 1;
  const int row0 = blockIdx.y * 128;
  const int col0 = blockIdx.x * 128;
  const int sk = blockIdx.z;
  const int Klen = K / SPLITK;
  const int k0 = sk * Klen;
  const int nsteps = Klen >> 6;

  const u16* Ab = A + (size_t)row0 * K + k0;
  const u16* Bb = Bt + (size_t)col0 * K + k0;

  f32x4 acc[4][4] = {};

  stage_tile(Ab, K, As[0], tid);
  stage_tile(Bb, K, Bs[0], tid);
  __syncthreads();

  int buf = 0;
  for (int ks = 0; ks < nsteps; ++ks) {
    if (ks + 1 < nsteps) {
      stage_tile(Ab + (ks + 1) * 64, K, As[buf ^ 1], tid);
      stage_tile(Bb + (ks + 1) * 64, K, Bs[buf ^ 1], tid);
    }
#pragma unroll
    for (int half = 0; half < 2; ++half) {
      const int kk = half * 32;
      bf16x8 af[4], bfr[4];
#pragma unroll
      for (int mi = 0; mi < 4; ++mi) {
        int r = wm * 64 + mi * 16 + (lane & 15);
        int c = (kk >> 3) + (lane >> 4);
        int slot = c ^ (r & 7);
        af[mi] = *(const bf16x8*)&As[buf][(r * 8 + slot) * 8];
      }
#pragma unroll
      for (int ni = 0; ni < 4; ++ni) {
        int r = wn * 64 + ni * 16 + (lane & 15);
        int c = (kk >> 3) + (lane >> 4);
        int slot = c ^ (r & 7);
        bfr[ni] = *(const bf16x8*)&Bs[buf][(r * 8 + slot) * 8];
      }
#pragma unroll
      for (int mi = 0; mi < 4; ++mi)
#pragma unroll
        for (int ni = 0; ni < 4; ++ni)
          acc[mi][ni] = __builtin_amdgcn_mfma_f32_16x16x32_bf16(af[mi], bfr[ni], acc[mi][ni], 0, 0, 0);
    }
    __syncthreads();
    buf ^= 1;
  }

  const int rbase = row0 + wm * 64 + (lane >> 4) * 4;
  const int cbase = col0 + wn * 64 + (lane & 15);
#pragma unroll
  for (int mi = 0; mi < 4; ++mi) {
#pragma unroll
    for (int ni = 0; ni < 4; ++ni) {
      int n = cbase + ni * 16;
#pragma unroll
      for (int r = 0; r < 4; ++r) {
        int t = rbase + mi * 16 + r;
        float val = acc[mi][ni][r];
        if (MODE == 0) {
          ((float*)Cv)[(size_t)sk * M * N + (size_t)t * N + n] = val;
        } else {
          int which = n >> 10, within = n & 1023;
          int h = within >> 6, d = within & 63;
          ((u16*)Cv)[(size_t)which * (NH * TT * HD) + (size_t)h * (TT * HD) +
                     (size_t)t * HD + d] = f2bf(val);
        }
      }
    }
  }
}

__global__ __launch_bounds__(256) void reduce_out(const float* __restrict__ P,
                                                  float* __restrict__ out) {
  int i = blockIdx.x * 256 + threadIdx.x;
  f32x4 a = ((const f32x4*)P)[i];
  a += ((const f32x4*)(P + (size_t)TT * NE))[i];
  a += ((const f32x4*)(P + 2 * (size_t)TT * NE))[i];
  a += ((const f32x4*)(P + 3 * (size_t)TT * NE))[i];
  ((f32x4*)out)[i] = a;
}

// ---- Tiled gathered attention ----
// One block per (h, 16-row tile). Neighbor superset of the 16 rows = exactly
// <=128 columns: 80 window rows [t0-64, t0+15], <=16 landmarks (j%64==0,
// j<t0-64), 32 scattered prev/next (= entries 0,1 of each neigh row), deduped.
// Coalesced K/V staging into LDS, QK^T via MFMA, structural mask, row-team
// softmax, PV via broadcast VALU loop. Each distinct j occupies exactly one
// live column, so masked softmax over the superset == reference.
__global__ __launch_bounds__(256) void attn3(const u16* __restrict__ qkv,
                                             const int* __restrict__ nidx,
                                             u16* __restrict__ y, int D) {
  __shared__ u16 Qs[16 * 64];
  __shared__ u16 Ks[128 * 64];     // overlaid by S (16x132 f32) after QK
  __shared__ u16 Vs[128 * 64];
  __shared__ int pn_l[32];
  __shared__ int colj[128];
  __shared__ float rinv[16];
  float* S = (float*)Ks;

  const int tid = threadIdx.x;
  const int lane = tid & 63;
  const int wv = tid >> 6;
  const int h = blockIdx.y;
  const int t0 = blockIdx.x * 16;

  const u16* qh = qkv + (size_t)h * TT * HD;
  const u16* kh = qkv + (size_t)NH * TT * HD + (size_t)h * TT * HD;
  const u16* vh = qkv + 2 * (size_t)NH * TT * HD + (size_t)h * TT * HD;

  // prev/next pairs = first two entries of each neighbor row
  if (tid < 32) pn_l[tid] = nidx[((size_t)h * TT + t0 + (tid >> 1)) * D + (tid & 1)];
  __syncthreads();

  // column map
  if (tid < 128) {
    int c = tid, j;
    if (c < 80) {
      j = t0 - 64 + c;
      if (j < 0) j = -1;
    } else if (c < 96) {
      j = (c - 80) * 64;
      if (j >= t0 - 64) j = -1;
    } else {
      int s = c - 96;
      j = pn_l[s];
      bool keep = (j < t0 - 64) && ((j & 63) != 0);
      if (keep) {
        for (int s2 = 0; s2 < s; ++s2)
          if (pn_l[s2] == j) { keep = false; break; }
      }
      if (!keep) j = -1;
    }
    colj[c] = j;
  }
  __syncthreads();

  // stage Q (chunk-swizzled), K (chunk-swizzled), V (linear) -- all coalesced
  if (tid < 128) {
    int row = tid >> 3, slot = tid & 7, ch = slot ^ (row & 7);
    gload16(qh + (size_t)(t0 + row) * HD + ch * 8, Qs + tid * 8);
  }
#pragma unroll
  for (int it = 0; it < 4; ++it) {
    int idx = it * 256 + tid;
    int col = idx >> 3, slot = idx & 7, ch = slot ^ (col & 7);
    int j = colj[col]; if (j < 0) j = 0;
    gload16(kh + (size_t)j * HD + ch * 8, Ks + idx * 8);
  }
#pragma unroll
  for (int it = 0; it < 4; ++it) {
    int idx = it * 256 + tid;
    int col = idx >> 3, ch = idx & 7;
    int j = colj[col]; if (j < 0) j = 0;
    gload16(vh + (size_t)j * HD + ch * 8, Vs + idx * 8);
  }
  __syncthreads();

  // QK^T: wave wv computes col-tiles 2wv, 2wv+1
  f32x4 sc[2] = {};
  bf16x8 af[2];
#pragma unroll
  for (int half = 0; half < 2; ++half) {
    int row = lane & 15;
    int chunk = 4 * half + (lane >> 4);
    af[half] = *(const bf16x8*)&Qs[row * 64 + (chunk ^ (row & 7)) * 8];
  }
#pragma unroll
  for (int p = 0; p < 2; ++p) {
    int col = 16 * (2 * wv + p) + (lane & 15);
#pragma unroll
    for (int half = 0; half < 2; ++half) {
      int chunk = 4 * half + (lane >> 4);
      bf16x8 bfv = *(const bf16x8*)&Ks[col * 64 + (chunk ^ (col & 7)) * 8];
      sc[p] = __builtin_amdgcn_mfma_f32_16x16x32_bf16(af[half], bfv, sc[p], 0, 0, 0);
    }
  }
  __syncthreads();   // all waves done reading Ks; S may overlay it now

  // mask + write scores
#pragma unroll
  for (int p = 0; p < 2; ++p) {
    int col = 16 * (2 * wv + p) + (lane & 15);
    int j = colj[col];
#pragma unroll
    for (int r = 0; r < 4; ++r) {
      int row = (lane >> 4) * 4 + r;
      int i = t0 + row;
      int p0 = pn_l[2 * row], p1 = pn_l[2 * row + 1];
      bool m;
      if (col < 80)      m = (j >= 0) && (j <= i) &&
                             ((i - j) <= 64 || (j & 63) == 0 || j == p0 || j == p1);
      else if (col < 96) m = (j >= 0);
      else               m = (j >= 0) && (j == p0 || j == p1);
      S[row * 132 + col] = m ? ((float)sc[p][r]) * 0.125f : -1e30f;
    }
  }
  __syncthreads();

  // row-team softmax: 16 threads per row, 8 cols each
  {
    int row = tid >> 4, q = tid & 15;
    float v[8];
    float mx = -3e38f;
#pragma unroll
    for (int e = 0; e < 8; ++e) {
      v[e] = S[row * 132 + q + 16 * e];
      mx = fmaxf(mx, v[e]);
    }
#pragma unroll
    for (int off = 1; off < 16; off <<= 1) mx = fmaxf(mx, __shfl_xor(mx, off, 64));
    float sum = 0.f;
#pragma unroll
    for (int e = 0; e < 8; ++e) {
      v[e] = __expf(v[e] - mx);
      sum += v[e];
    }
#pragma unroll
    for (int off = 1; off < 16; off <<= 1) sum += __shfl_xor(sum, off, 64);
#pragma unroll
    for (int e = 0; e < 8; ++e) S[row * 132 + q + 16 * e] = v[e];
    if (q == 0) rinv[row] = 1.0f / sum;
  }
  __syncthreads();

  // PV: thread (i, dq) accumulates out[i][4dq..4dq+3] over 128 cols (all LDS)
  {
    int i = tid >> 4, dq = tid & 15;
    float a0 = 0.f, a1 = 0.f, a2 = 0.f, a3 = 0.f;
    const float* Srow = S + i * 132;
#pragma unroll 8
    for (int k = 0; k < 128; ++k) {
      float w = Srow[k];
      uint2 vv2 = *(const uint2*)&Vs[k * 64 + dq * 4];
      a0 = fmaf(w, __builtin_bit_cast(float, vv2.x << 16), a0);
      a1 = fmaf(w, __builtin_bit_cast(float, vv2.x & 0xffff0000u), a1);
      a2 = fmaf(w, __builtin_bit_cast(float, vv2.y << 16), a2);
      a3 = fmaf(w, __builtin_bit_cast(float, vv2.y & 0xffff0000u), a3);
    }
    float inv = rinv[i];
    ushort4 o = {f2bf(a0 * inv), f2bf(a1 * inv), f2bf(a2 * inv), f2bf(a3 * inv)};
    *(ushort4*)&y[(size_t)(t0 + i) * NE + h * HD + dq * 4] = o;
  }
}

extern "C" void kernel_launch(void* const* d_in, const int* in_sizes, int n_in,
                              void* d_out, int out_size, void* d_ws, size_t ws_size,
                              hipStream_t stream) {
  const float* x    = (const float*)d_in[0];
  const float* Wqkv = (const float*)d_in[1];
  const float* Wout = (const float*)d_in[2];
  const int*   nidx = (const int*)d_in[3];
  float* out = (float*)d_out;

  u16* ws16  = (u16*)d_ws;
  u16* xb    = ws16;                 // 2MB; reused as y after gemm1
  u16* WqkvT = ws16 + 1048576;       // 6MB
  u16* WoutT = ws16 + 4194304;       // 2MB
  u16* qkvb  = ws16 + 5242880;       // 6MB
  float* Pout = (float*)((char*)d_ws + (32u << 20));  // 4 x 4MB f32 partials

  const int D = in_sizes[3] / (NH * TT);   // 83

  f32_to_bf16<<<1024, 256, 0, stream>>>(x, xb);
  transpose_both<<<dim3(64, 16), 256, 0, stream>>>(Wqkv, Wout, WqkvT, WoutT);

  // qkv = x @ Wqkv  (scatter epilogue into [which][h][t][d] bf16)
  gemm128<1, 1><<<dim3(24, 8, 1), 256, 0, stream>>>(xb, WqkvT, qkvb, TT, 3 * NE, NE);

  // tiled gathered attention; y (bf16) overlays xb
  attn3<<<dim3(TT / 16, NH), 256, 0, stream>>>(qkvb, nidx, xb, D);

  // out = y @ Wout, split-K=4 partials then reduce
  gemm128<0, 4><<<dim3(8, 8, 4), 256, 0, stream>>>(xb, WoutT, Pout, TT, NE, NE);
  reduce_out<<<TT * NE / 4 / 256, 256, 0, stream>>>(Pout, out);
}

// Round 6
// 53.799 us; speedup vs baseline: 6.3561x; 1.2386x over previous
//
#include <hip/hip_runtime.h>
#include <math.h>

#define NH 16
#define TT 1024
#define HD 64
#define NE 1024

typedef unsigned int u32;
typedef unsigned short u16;
typedef __bf16 bf16x8 __attribute__((ext_vector_type(8)));
typedef float f32x4 __attribute__((ext_vector_type(4)));

__device__ inline u16 f2bf(float f) {
  u32 u = __builtin_bit_cast(u32, f);
  u32 r = (u + 0x7fffu + ((u >> 16) & 1u)) >> 16;
  return (u16)r;
}
__device__ inline float bf2f(u16 h) {
  return __builtin_bit_cast(float, (u32)h << 16);
}
__device__ inline void gload16(const void* g, void* l) {
  __builtin_amdgcn_global_load_lds((const __attribute__((address_space(1))) void*)g,
                                   (__attribute__((address_space(3))) void*)l, 16, 0, 0);
}

// Fused prep: blocks [0,1024) convert x -> bf16; [1024,2048) transpose weights.
__global__ __launch_bounds__(256) void prep(const float* __restrict__ x,
                                            const float* __restrict__ Wqkv,
                                            const float* __restrict__ Wout,
                                            u16* __restrict__ xb,
                                            u16* __restrict__ WqkvT,
                                            u16* __restrict__ WoutT) {
  __shared__ float tile[64][65];
  const int tid = threadIdx.x;
  const int bx = blockIdx.x;
  if (bx < 1024) {
    int i = bx * 256 + tid;
    float4 f = ((const float4*)x)[i];
    ushort4 o = {f2bf(f.x), f2bf(f.y), f2bf(f.z), f2bf(f.w)};
    ((ushort4*)xb)[i] = o;
    return;
  }
  int b = bx - 1024;
  int nb = b & 63, kb = b >> 6;
  const float* W; u16* WT; int N, n0;
  if (nb < 48) { W = Wqkv; WT = WqkvT; N = 3 * NE; n0 = nb * 64; }
  else         { W = Wout; WT = WoutT; N = NE;     n0 = (nb - 48) * 64; }
  const int k0 = kb * 64;
#pragma unroll
  for (int it = 0; it < 16; ++it) {
    int idx = it * 256 + tid;
    int r = idx >> 6, c = idx & 63;
    tile[r][c] = W[(size_t)(k0 + r) * N + n0 + c];
  }
  __syncthreads();
#pragma unroll
  for (int it = 0; it < 16; ++it) {
    int idx = it * 256 + tid;
    int nn = idx >> 6, kk = idx & 63;
    WT[(size_t)(n0 + nn) * NE + k0 + kk] = f2bf(tile[kk][nn]);
  }
}

// Stage R rows x 64 k of bf16 into LDS, chunk-swizzled: slot(r,kg)=kg^(r&7).
template<int R>
__device__ __forceinline__ void stage_rows(const u16* __restrict__ G, int ldk,
                                           u16* L, int tid) {
#pragma unroll
  for (int it = 0; it < R / 32; ++it) {
    int idx = it * 256 + tid;
    int r = idx >> 3, kg = idx & 7;
    gload16(G + (size_t)r * ldk + ((kg ^ (r & 7)) << 3), L + (idx << 3));
  }
}

// bf16 MFMA GEMM: 128 x NT tile, BK=64, 4 waves (2x2), dbuf, swizzled LDS.
// Writes f32 split-K partials: C[sk*M*N + t*N + n].
template<int SPLITK, int NT>
__global__ __launch_bounds__(256) void gemm_bt(const u16* __restrict__ A,
                                               const u16* __restrict__ Bt,
                                               float* __restrict__ C,
                                               int M, int N, int K) {
  __shared__ u16 As[2][128 * 64];
  __shared__ u16 Bs[2][NT * 64];
  const int tid = threadIdx.x;
  const int lane = tid & 63;
  const int wv = tid >> 6;
  const int wm = wv >> 1, wn = wv & 1;
  const int row0 = blockIdx.y * 128;
  const int col0 = blockIdx.x * NT;
  const int sk = blockIdx.z;
  const int Klen = K / SPLITK;
  const int nsteps = Klen >> 6;
  constexpr int NI = NT / 32;

  const u16* Ab = A + (size_t)row0 * K + sk * Klen;
  const u16* Bb = Bt + (size_t)col0 * K + sk * Klen;

  f32x4 acc[4][NI] = {};

  stage_rows<128>(Ab, K, As[0], tid);
  stage_rows<NT>(Bb, K, Bs[0], tid);
  __syncthreads();

  int buf = 0;
  for (int ks = 0; ks < nsteps; ++ks) {
    if (ks + 1 < nsteps) {
      stage_rows<128>(Ab + (ks + 1) * 64, K, As[buf ^ 1], tid);
      stage_rows<NT>(Bb + (ks + 1) * 64, K, Bs[buf ^ 1], tid);
    }
#pragma unroll
    for (int half = 0; half < 2; ++half) {
      const int kk = half * 32;
      bf16x8 af[4], bfr[NI];
#pragma unroll
      for (int mi = 0; mi < 4; ++mi) {
        int r = wm * 64 + mi * 16 + (lane & 15);
        int c = (kk >> 3) + (lane >> 4);
        af[mi] = *(const bf16x8*)&As[buf][(r * 8 + (c ^ (r & 7))) * 8];
      }
#pragma unroll
      for (int ni = 0; ni < NI; ++ni) {
        int r = wn * (NT / 2) + ni * 16 + (lane & 15);
        int c = (kk >> 3) + (lane >> 4);
        bfr[ni] = *(const bf16x8*)&Bs[buf][(r * 8 + (c ^ (r & 7))) * 8];
      }
#pragma unroll
      for (int mi = 0; mi < 4; ++mi)
#pragma unroll
        for (int ni = 0; ni < NI; ++ni)
          acc[mi][ni] = __builtin_amdgcn_mfma_f32_16x16x32_bf16(af[mi], bfr[ni], acc[mi][ni], 0, 0, 0);
    }
    __syncthreads();
    buf ^= 1;
  }

  const int rbase = row0 + wm * 64 + (lane >> 4) * 4;
  const int cbase = col0 + wn * (NT / 2) + (lane & 15);
  float* Cp = C + (size_t)sk * M * N;
#pragma unroll
  for (int mi = 0; mi < 4; ++mi)
#pragma unroll
    for (int ni = 0; ni < NI; ++ni)
#pragma unroll
      for (int r = 0; r < 4; ++r)
        Cp[(size_t)(rbase + mi * 16 + r) * N + cbase + ni * 16] = acc[mi][ni][r];
}

// qkv partials: add 2, convert bf16, scatter [which][h][t][d]. grid (3,1024).
__global__ __launch_bounds__(256) void reduce_qkv(const float* __restrict__ Pg,
                                                  u16* __restrict__ qkvb) {
  const int t = blockIdx.y;
  const int n4 = blockIdx.x * 256 + threadIdx.x;   // 0..767
  const int i = t * 768 + n4;
  f32x4 a = ((const f32x4*)Pg)[i];
  a += ((const f32x4*)(Pg + (size_t)TT * 3 * NE))[i];
  int n = n4 * 4;
  int which = n >> 10, h = (n & 1023) >> 6, d = n & 63;
  ushort4 o = {f2bf(a[0]), f2bf(a[1]), f2bf(a[2]), f2bf(a[3])};
  *(ushort4*)&qkvb[(size_t)which * (NH * TT * HD) + (size_t)h * (TT * HD) +
                   (size_t)t * HD + d] = o;
}

__global__ __launch_bounds__(256) void reduce_out(const float* __restrict__ P,
                                                  float* __restrict__ out) {
  int i = blockIdx.x * 256 + threadIdx.x;
  f32x4 a = ((const f32x4*)P)[i];
  a += ((const f32x4*)(P + (size_t)TT * NE))[i];
  a += ((const f32x4*)(P + 2 * (size_t)TT * NE))[i];
  a += ((const f32x4*)(P + 3 * (size_t)TT * NE))[i];
  ((f32x4*)out)[i] = a;
}

// Tiled gathered attention, MFMA QK^T + MFMA PV.
// One block per (h, 16-row tile); <=128 superset columns (proved r4: 80 window,
// 16 landmarks, 32 prev/next dedup'd).
__global__ __launch_bounds__(256) void attn4(const u16* __restrict__ qkv,
                                             const int* __restrict__ nidx,
                                             u16* __restrict__ y, int D) {
  __shared__ __align__(16) u16 Qs[16 * 64];     // 2KB
  __shared__ __align__(16) u16 Ks[128 * 64];    // 16KB; S f32[16][132] overlays [0,8448); P bf16 at +8448
  __shared__ __align__(16) u16 Vt[64 * 128];    // 16KB, swizzled [d][k]
  __shared__ int pn_l[32];
  __shared__ int colj[128];
  __shared__ float rinv[16];
  float* S = (float*)Ks;
  u16* P = (u16*)((char*)Ks + 8448);

  const int tid = threadIdx.x;
  const int lane = tid & 63;
  const int wv = tid >> 6;
  const int h = blockIdx.y;
  const int t0 = blockIdx.x * 16;

  const u16* qh = qkv + (size_t)h * TT * HD;
  const u16* kh = qkv + (size_t)NH * TT * HD + (size_t)h * TT * HD;
  const u16* vh = qkv + 2 * (size_t)NH * TT * HD + (size_t)h * TT * HD;

  if (tid < 32) pn_l[tid] = nidx[((size_t)h * TT + t0 + (tid >> 1)) * D + (tid & 1)];
  __syncthreads();

  if (tid < 128) {
    int c = tid, j;
    if (c < 80) {
      j = t0 - 64 + c;
      if (j < 0) j = -1;
    } else if (c < 96) {
      j = (c - 80) * 64;
      if (j >= t0 - 64) j = -1;
    } else {
      int s = c - 96;
      j = pn_l[s];
      bool keep = (j < t0 - 64) && ((j & 63) != 0);
      if (keep)
        for (int s2 = 0; s2 < s; ++s2)
          if (pn_l[s2] == j) { keep = false; break; }
      if (!keep) j = -1;
    }
    colj[c] = j;
  }
  __syncthreads();

  // stage Q,K via global_load_lds (chunk-swizzled); V -> registers
  if (tid < 128) {
    int row = tid >> 3, slot = tid & 7, ch = slot ^ (row & 7);
    gload16(qh + (size_t)(t0 + row) * HD + ch * 8, Qs + tid * 8);
  }
  uint4 vreg[4];
#pragma unroll
  for (int it = 0; it < 4; ++it) {
    int idx = it * 256 + tid;
    int col = idx >> 3, slot = idx & 7, ch = slot ^ (col & 7);
    int j = colj[col]; if (j < 0) j = 0;
    gload16(kh + (size_t)j * HD + ch * 8, Ks + idx * 8);
  }
#pragma unroll
  for (int it = 0; it < 4; ++it) {
    int idx = it * 256 + tid;
    int col = idx >> 3, ch = idx & 7;
    int j = colj[col]; if (j < 0) j = 0;
    vreg[it] = *(const uint4*)(vh + (size_t)j * HD + ch * 8);
  }
  __syncthreads();

  // QK^T: wave wv owns col-tiles 2wv, 2wv+1
  f32x4 sc[2] = {};
  bf16x8 af[2];
#pragma unroll
  for (int half = 0; half < 2; ++half) {
    int row = lane & 15;
    int chunk = 4 * half + (lane >> 4);
    af[half] = *(const bf16x8*)&Qs[(row * 8 + (chunk ^ (row & 7))) * 8];
  }
#pragma unroll
  for (int p = 0; p < 2; ++p) {
    int col = 16 * (2 * wv + p) + (lane & 15);
#pragma unroll
    for (int half = 0; half < 2; ++half) {
      int chunk = 4 * half + (lane >> 4);
      bf16x8 bfv = *(const bf16x8*)&Ks[(col * 8 + (chunk ^ (col & 7))) * 8];
      sc[p] = __builtin_amdgcn_mfma_f32_16x16x32_bf16(af[half], bfv, sc[p], 0, 0, 0);
    }
  }
  __syncthreads();   // done reading Ks; S may overlay

  // mask + S write
#pragma unroll
  for (int p = 0; p < 2; ++p) {
    int col = 16 * (2 * wv + p) + (lane & 15);
    int j = colj[col];
#pragma unroll
    for (int r = 0; r < 4; ++r) {
      int row = (lane >> 4) * 4 + r;
      int i = t0 + row;
      int p0 = pn_l[2 * row], p1 = pn_l[2 * row + 1];
      bool m;
      if (col < 80)      m = (j >= 0) && (j <= i) &&
                             ((i - j) <= 64 || (j & 63) == 0 || j == p0 || j == p1);
      else if (col < 96) m = (j >= 0);
      else               m = (j >= 0) && (j == p0 || j == p1);
      S[row * 132 + col] = m ? ((float)sc[p][r]) * 0.125f : -1e30f;
    }
  }
  __syncthreads();

  // softmax (row team = 16 lanes, 8 contiguous cols each) + P(bf16) write
  {
    int row = tid >> 4, q = tid & 15;
    float v[8];
    float mx = -3e38f;
#pragma unroll
    for (int e = 0; e < 8; ++e) {
      v[e] = S[row * 132 + 8 * q + e];
      mx = fmaxf(mx, v[e]);
    }
#pragma unroll
    for (int off = 1; off < 16; off <<= 1) mx = fmaxf(mx, __shfl_xor(mx, off, 64));
    float sum = 0.f;
#pragma unroll
    for (int e = 0; e < 8; ++e) {
      v[e] = __expf(v[e] - mx);
      sum += v[e];
    }
#pragma unroll
    for (int off = 1; off < 16; off <<= 1) sum += __shfl_xor(sum, off, 64);
    if (q == 0) rinv[row] = 1.0f / sum;
    u32 w0 = (u32)f2bf(v[0]) | ((u32)f2bf(v[1]) << 16);
    u32 w1 = (u32)f2bf(v[2]) | ((u32)f2bf(v[3]) << 16);
    u32 w2 = (u32)f2bf(v[4]) | ((u32)f2bf(v[5]) << 16);
    u32 w3 = (u32)f2bf(v[6]) | ((u32)f2bf(v[7]) << 16);
    uint4 pk = {w0, w1, w2, w3};
    *(uint4*)&P[row * 128 + ((q ^ (row & 7)) << 3)] = pk;
  }

  // Vt transpose-write: Vt[d][k], slot swz = (k>>3) ^ (d&7) ^ (d>>3)
#pragma unroll
  for (int it = 0; it < 4; ++it) {
    int idx = it * 256 + tid;
    int col = idx >> 3, ch = idx & 7;
    const u32* vw = (const u32*)&vreg[it];
#pragma unroll
    for (int e = 0; e < 8; ++e) {
      int d = ch * 8 + e;
      u16 val = (e & 1) ? (u16)(vw[e >> 1] >> 16) : (u16)(vw[e >> 1] & 0xffffu);
      int swz = (col >> 3) ^ e ^ ch;
      Vt[d * 128 + swz * 8 + (col & 7)] = val;
    }
  }
  __syncthreads();

  // PV: wave wv owns d-tile wv. out 16x16 per wave.
  f32x4 oacc = {};
#pragma unroll
  for (int ks2 = 0; ks2 < 4; ++ks2) {
    int rowp = lane & 15;
    int chp = ks2 * 4 + (lane >> 4);
    bf16x8 pa = *(const bf16x8*)&P[rowp * 128 + ((chp ^ (rowp & 7)) << 3)];
    int dd = wv * 16 + (lane & 15);
    int swz = chp ^ (dd & 7) ^ ((dd >> 3) & 7);
    bf16x8 vb = *(const bf16x8*)&Vt[dd * 128 + swz * 8];
    oacc = __builtin_amdgcn_mfma_f32_16x16x32_bf16(pa, vb, oacc, 0, 0, 0);
  }
  {
    int dd = wv * 16 + (lane & 15);
#pragma unroll
    for (int r = 0; r < 4; ++r) {
      int row = (lane >> 4) * 4 + r;
      y[(size_t)(t0 + row) * NE + h * HD + dd] = f2bf(oacc[r] * rinv[row]);
    }
  }
}

extern "C" void kernel_launch(void* const* d_in, const int* in_sizes, int n_in,
                              void* d_out, int out_size, void* d_ws, size_t ws_size,
                              hipStream_t stream) {
  const float* x    = (const float*)d_in[0];
  const float* Wqkv = (const float*)d_in[1];
  const float* Wout = (const float*)d_in[2];
  const int*   nidx = (const int*)d_in[3];
  float* out = (float*)d_out;

  u16* ws16  = (u16*)d_ws;
  u16* xb    = ws16;                 // 2MB; reused as y after gemm1
  u16* WqkvT = ws16 + 1048576;       // 6MB
  u16* WoutT = ws16 + 4194304;       // 2MB
  u16* qkvb  = ws16 + 5242880;       // 6MB
  float* Pg   = (float*)((char*)d_ws + (16u << 20));  // 2 x 12MB gemm1 partials
  float* Pout = (float*)((char*)d_ws + (40u << 20));  // 4 x 4MB gemm2 partials

  const int D = in_sizes[3] / (NH * TT);   // 83

  prep<<<2048, 256, 0, stream>>>(x, Wqkv, Wout, xb, WqkvT, WoutT);

  // qkv partials = x @ Wqkv (split-K=2, 768 blocks)
  gemm_bt<2, 64><<<dim3(48, 8, 2), 256, 0, stream>>>(xb, WqkvT, Pg, TT, 3 * NE, NE);
  reduce_qkv<<<dim3(3, TT), 256, 0, stream>>>(Pg, qkvb);

  // tiled gathered attention; y (bf16) overlays xb
  attn4<<<dim3(TT / 16, NH), 256, 0, stream>>>(qkvb, nidx, xb, D);

  // out = y @ Wout (split-K=4, 512 blocks)
  gemm_bt<4, 64><<<dim3(16, 8, 4), 256, 0, stream>>>(xb, WoutT, Pout, TT, NE, NE);
  reduce_out<<<TT * NE / 4 / 256, 256, 0, stream>>>(Pout, out);
}

// Round 7
// 46.458 us; speedup vs baseline: 7.3604x; 1.1580x over previous
//
#include <hip/hip_runtime.h>
#include <math.h>

#define NH 16
#define TT 1024
#define HD 64
#define NE 1024

typedef unsigned int u32;
typedef unsigned short u16;
typedef __bf16 bf16x8 __attribute__((ext_vector_type(8)));
typedef float f32x4 __attribute__((ext_vector_type(4)));

__device__ inline u16 f2bf(float f) {
  u32 u = __builtin_bit_cast(u32, f);
  u32 r = (u + 0x7fffu + ((u >> 16) & 1u)) >> 16;
  return (u16)r;
}
__device__ inline float bf2f(u16 h) {
  return __builtin_bit_cast(float, (u32)h << 16);
}
__device__ inline void gload16(const void* g, void* l) {
  __builtin_amdgcn_global_load_lds((const __attribute__((address_space(1))) void*)g,
                                   (__attribute__((address_space(3))) void*)l, 16, 0, 0);
}

// Fused prep: blocks [0,1024) convert x -> bf16; [1024,2048) transpose weights.
__global__ __launch_bounds__(256) void prep(const float* __restrict__ x,
                                            const float* __restrict__ Wqkv,
                                            const float* __restrict__ Wout,
                                            u16* __restrict__ xb,
                                            u16* __restrict__ WqkvT,
                                            u16* __restrict__ WoutT) {
  __shared__ float tile[64][65];
  const int tid = threadIdx.x;
  const int bx = blockIdx.x;
  if (bx < 1024) {
    int i = bx * 256 + tid;
    float4 f = ((const float4*)x)[i];
    ushort4 o = {f2bf(f.x), f2bf(f.y), f2bf(f.z), f2bf(f.w)};
    ((ushort4*)xb)[i] = o;
    return;
  }
  int b = bx - 1024;
  int nb = b & 63, kb = b >> 6;
  const float* W; u16* WT; int N, n0;
  if (nb < 48) { W = Wqkv; WT = WqkvT; N = 3 * NE; n0 = nb * 64; }
  else         { W = Wout; WT = WoutT; N = NE;     n0 = (nb - 48) * 64; }
  const int k0 = kb * 64;
#pragma unroll
  for (int it = 0; it < 16; ++it) {
    int idx = it * 256 + tid;
    int r = idx >> 6, c = idx & 63;
    tile[r][c] = W[(size_t)(k0 + r) * N + n0 + c];
  }
  __syncthreads();
#pragma unroll
  for (int it = 0; it < 16; ++it) {
    int idx = it * 256 + tid;
    int nn = idx >> 6, kk = idx & 63;
    WT[(size_t)(n0 + nn) * NE + k0 + kk] = f2bf(tile[kk][nn]);
  }
}

// Stage R rows x 64 k of bf16 into LDS, chunk-swizzled: slot(r,kg)=kg^(r&7).
template<int R>
__device__ __forceinline__ void stage_rows(const u16* __restrict__ G, int ldk,
                                           u16* L, int tid) {
#pragma unroll
  for (int it = 0; it < R / 32; ++it) {
    int idx = it * 256 + tid;
    int r = idx >> 3, kg = idx & 7;
    gload16(G + (size_t)r * ldk + ((kg ^ (r & 7)) << 3), L + (idx << 3));
  }
}

// bf16 MFMA GEMM, no split-K: 64 x NT tile, BK=64, 4 waves (2x2), dbuf,
// swizzled LDS. High grid-residency replaces split-K (no partials/reduce).
// MODE 0: f32 direct write. MODE 1: bf16 qkv scatter [which][h][t][d].
template<int MODE, int NT>
__global__ __launch_bounds__(256) void gemm_direct(const u16* __restrict__ A,
                                                   const u16* __restrict__ Bt,
                                                   void* __restrict__ Cv,
                                                   int M, int N, int K) {
  __shared__ u16 As[2][64 * 64];
  __shared__ u16 Bs[2][NT * 64];
  const int tid = threadIdx.x;
  const int lane = tid & 63;
  const int wv = tid >> 6;
  const int wm = wv >> 1, wn = wv & 1;
  const int row0 = blockIdx.y * 64;
  const int col0 = blockIdx.x * NT;
  const int nsteps = K >> 6;
  constexpr int NI = NT / 32;

  const u16* Ab = A + (size_t)row0 * K;
  const u16* Bb = Bt + (size_t)col0 * K;

  f32x4 acc[2][NI] = {};

  stage_rows<64>(Ab, K, As[0], tid);
  stage_rows<NT>(Bb, K, Bs[0], tid);
  __syncthreads();

  int buf = 0;
  for (int ks = 0; ks < nsteps; ++ks) {
    if (ks + 1 < nsteps) {
      stage_rows<64>(Ab + (ks + 1) * 64, K, As[buf ^ 1], tid);
      stage_rows<NT>(Bb + (ks + 1) * 64, K, Bs[buf ^ 1], tid);
    }
#pragma unroll
    for (int half = 0; half < 2; ++half) {
      const int kk = half * 32;
      bf16x8 af[2], bfr[NI];
#pragma unroll
      for (int mi = 0; mi < 2; ++mi) {
        int r = wm * 32 + mi * 16 + (lane & 15);
        int c = (kk >> 3) + (lane >> 4);
        af[mi] = *(const bf16x8*)&As[buf][(r * 8 + (c ^ (r & 7))) * 8];
      }
#pragma unroll
      for (int ni = 0; ni < NI; ++ni) {
        int r = wn * (NT / 2) + ni * 16 + (lane & 15);
        int c = (kk >> 3) + (lane >> 4);
        bfr[ni] = *(const bf16x8*)&Bs[buf][(r * 8 + (c ^ (r & 7))) * 8];
      }
#pragma unroll
      for (int mi = 0; mi < 2; ++mi)
#pragma unroll
        for (int ni = 0; ni < NI; ++ni)
          acc[mi][ni] = __builtin_amdgcn_mfma_f32_16x16x32_bf16(af[mi], bfr[ni], acc[mi][ni], 0, 0, 0);
    }
    __syncthreads();
    buf ^= 1;
  }

  const int rbase = row0 + wm * 32 + (lane >> 4) * 4;
  const int cbase = col0 + wn * (NT / 2) + (lane & 15);
#pragma unroll
  for (int mi = 0; mi < 2; ++mi) {
#pragma unroll
    for (int ni = 0; ni < NI; ++ni) {
      int n = cbase + ni * 16;
#pragma unroll
      for (int r = 0; r < 4; ++r) {
        int t = rbase + mi * 16 + r;
        float val = acc[mi][ni][r];
        if (MODE == 0) {
          ((float*)Cv)[(size_t)t * N + n] = val;
        } else {
          int which = n >> 10, h = (n & 1023) >> 6, d = n & 63;
          ((u16*)Cv)[(size_t)which * (NH * TT * HD) + (size_t)h * (TT * HD) +
                     (size_t)t * HD + d] = f2bf(val);
        }
      }
    }
  }
}

// Tiled gathered attention, MFMA QK^T + MFMA PV.
// One block per (h, 16-row tile); <=128 superset columns (80 window,
// 16 landmarks, 32 prev/next dedup'd).
__global__ __launch_bounds__(256) void attn4(const u16* __restrict__ qkv,
                                             const int* __restrict__ nidx,
                                             u16* __restrict__ y, int D) {
  __shared__ __align__(16) u16 Qs[16 * 64];     // 2KB
  __shared__ __align__(16) u16 Ks[128 * 64];    // 16KB; S f32[16][132] overlays; P bf16 at +8448
  __shared__ __align__(16) u16 Vt[64 * 128];    // 16KB, swizzled [d][k]
  __shared__ int pn_l[32];
  __shared__ int colj[128];
  __shared__ float rinv[16];
  float* S = (float*)Ks;
  u16* P = (u16*)((char*)Ks + 8448);

  const int tid = threadIdx.x;
  const int lane = tid & 63;
  const int wv = tid >> 6;
  const int h = blockIdx.y;
  const int t0 = blockIdx.x * 16;

  const u16* qh = qkv + (size_t)h * TT * HD;
  const u16* kh = qkv + (size_t)NH * TT * HD + (size_t)h * TT * HD;
  const u16* vh = qkv + 2 * (size_t)NH * TT * HD + (size_t)h * TT * HD;

  if (tid < 32) pn_l[tid] = nidx[((size_t)h * TT + t0 + (tid >> 1)) * D + (tid & 1)];
  __syncthreads();

  if (tid < 128) {
    int c = tid, j;
    if (c < 80) {
      j = t0 - 64 + c;
      if (j < 0) j = -1;
    } else if (c < 96) {
      j = (c - 80) * 64;
      if (j >= t0 - 64) j = -1;
    } else {
      int s = c - 96;
      j = pn_l[s];
      bool keep = (j < t0 - 64) && ((j & 63) != 0);
      if (keep)
        for (int s2 = 0; s2 < s; ++s2)
          if (pn_l[s2] == j) { keep = false; break; }
      if (!keep) j = -1;
    }
    colj[c] = j;
  }
  __syncthreads();

  // stage Q,K via global_load_lds (chunk-swizzled); V -> registers
  if (tid < 128) {
    int row = tid >> 3, slot = tid & 7, ch = slot ^ (row & 7);
    gload16(qh + (size_t)(t0 + row) * HD + ch * 8, Qs + tid * 8);
  }
  uint4 vreg[4];
#pragma unroll
  for (int it = 0; it < 4; ++it) {
    int idx = it * 256 + tid;
    int col = idx >> 3, slot = idx & 7, ch = slot ^ (col & 7);
    int j = colj[col]; if (j < 0) j = 0;
    gload16(kh + (size_t)j * HD + ch * 8, Ks + idx * 8);
  }
#pragma unroll
  for (int it = 0; it < 4; ++it) {
    int idx = it * 256 + tid;
    int col = idx >> 3, ch = idx & 7;
    int j = colj[col]; if (j < 0) j = 0;
    vreg[it] = *(const uint4*)(vh + (size_t)j * HD + ch * 8);
  }
  __syncthreads();

  // QK^T: wave wv owns col-tiles 2wv, 2wv+1
  f32x4 sc[2] = {};
  bf16x8 af[2];
#pragma unroll
  for (int half = 0; half < 2; ++half) {
    int row = lane & 15;
    int chunk = 4 * half + (lane >> 4);
    af[half] = *(const bf16x8*)&Qs[(row * 8 + (chunk ^ (row & 7))) * 8];
  }
#pragma unroll
  for (int p = 0; p < 2; ++p) {
    int col = 16 * (2 * wv + p) + (lane & 15);
#pragma unroll
    for (int half = 0; half < 2; ++half) {
      int chunk = 4 * half + (lane >> 4);
      bf16x8 bfv = *(const bf16x8*)&Ks[(col * 8 + (chunk ^ (col & 7))) * 8];
      sc[p] = __builtin_amdgcn_mfma_f32_16x16x32_bf16(af[half], bfv, sc[p], 0, 0, 0);
    }
  }
  __syncthreads();   // done reading Ks; S may overlay

  // mask + S write
#pragma unroll
  for (int p = 0; p < 2; ++p) {
    int col = 16 * (2 * wv + p) + (lane & 15);
    int j = colj[col];
#pragma unroll
    for (int r = 0; r < 4; ++r) {
      int row = (lane >> 4) * 4 + r;
      int i = t0 + row;
      int p0 = pn_l[2 * row], p1 = pn_l[2 * row + 1];
      bool m;
      if (col < 80)      m = (j >= 0) && (j <= i) &&
                             ((i - j) <= 64 || (j & 63) == 0 || j == p0 || j == p1);
      else if (col < 96) m = (j >= 0);
      else               m = (j >= 0) && (j == p0 || j == p1);
      S[row * 132 + col] = m ? ((float)sc[p][r]) * 0.125f : -1e30f;
    }
  }
  __syncthreads();

  // softmax (row team = 16 lanes, 8 contiguous cols each) + P(bf16) write
  {
    int row = tid >> 4, q = tid & 15;
    float v[8];
    float mx = -3e38f;
#pragma unroll
    for (int e = 0; e < 8; ++e) {
      v[e] = S[row * 132 + 8 * q + e];
      mx = fmaxf(mx, v[e]);
    }
#pragma unroll
    for (int off = 1; off < 16; off <<= 1) mx = fmaxf(mx, __shfl_xor(mx, off, 64));
    float sum = 0.f;
#pragma unroll
    for (int e = 0; e < 8; ++e) {
      v[e] = __expf(v[e] - mx);
      sum += v[e];
    }
#pragma unroll
    for (int off = 1; off < 16; off <<= 1) sum += __shfl_xor(sum, off, 64);
    if (q == 0) rinv[row] = 1.0f / sum;
    u32 w0 = (u32)f2bf(v[0]) | ((u32)f2bf(v[1]) << 16);
    u32 w1 = (u32)f2bf(v[2]) | ((u32)f2bf(v[3]) << 16);
    u32 w2 = (u32)f2bf(v[4]) | ((u32)f2bf(v[5]) << 16);
    u32 w3 = (u32)f2bf(v[6]) | ((u32)f2bf(v[7]) << 16);
    uint4 pk = {w0, w1, w2, w3};
    *(uint4*)&P[row * 128 + ((q ^ (row & 7)) << 3)] = pk;
  }

  // Vt transpose-write: Vt[d][k], slot swz = (k>>3) ^ (d&7) ^ (d>>3)
#pragma unroll
  for (int it = 0; it < 4; ++it) {
    int idx = it * 256 + tid;
    int col = idx >> 3, ch = idx & 7;
    const u32* vw = (const u32*)&vreg[it];
#pragma unroll
    for (int e = 0; e < 8; ++e) {
      int d = ch * 8 + e;
      u16 val = (e & 1) ? (u16)(vw[e >> 1] >> 16) : (u16)(vw[e >> 1] & 0xffffu);
      int swz = (col >> 3) ^ e ^ ch;
      Vt[d * 128 + swz * 8 + (col & 7)] = val;
    }
  }
  __syncthreads();

  // PV: wave wv owns d-tile wv. out 16x16 per wave.
  f32x4 oacc = {};
#pragma unroll
  for (int ks2 = 0; ks2 < 4; ++ks2) {
    int rowp = lane & 15;
    int chp = ks2 * 4 + (lane >> 4);
    bf16x8 pa = *(const bf16x8*)&P[rowp * 128 + ((chp ^ (rowp & 7)) << 3)];
    int dd = wv * 16 + (lane & 15);
    int swz = chp ^ (dd & 7) ^ ((dd >> 3) & 7);
    bf16x8 vb = *(const bf16x8*)&Vt[dd * 128 + swz * 8];
    oacc = __builtin_amdgcn_mfma_f32_16x16x32_bf16(pa, vb, oacc, 0, 0, 0);
  }
  {
    int dd = wv * 16 + (lane & 15);
#pragma unroll
    for (int r = 0; r < 4; ++r) {
      int row = (lane >> 4) * 4 + r;
      y[(size_t)(t0 + row) * NE + h * HD + dd] = f2bf(oacc[r] * rinv[row]);
    }
  }
}

extern "C" void kernel_launch(void* const* d_in, const int* in_sizes, int n_in,
                              void* d_out, int out_size, void* d_ws, size_t ws_size,
                              hipStream_t stream) {
  const float* x    = (const float*)d_in[0];
  const float* Wqkv = (const float*)d_in[1];
  const float* Wout = (const float*)d_in[2];
  const int*   nidx = (const int*)d_in[3];
  float* out = (float*)d_out;

  u16* ws16  = (u16*)d_ws;
  u16* xb    = ws16;                 // 2MB; reused as y after gemm1
  u16* WqkvT = ws16 + 1048576;       // 6MB
  u16* WoutT = ws16 + 4194304;       // 2MB
  u16* qkvb  = ws16 + 5242880;       // 6MB

  const int D = in_sizes[3] / (NH * TT);   // 83

  prep<<<2048, 256, 0, stream>>>(x, Wqkv, Wout, xb, WqkvT, WoutT);

  // qkv = x @ Wqkv, bf16 scatter epilogue. 768 blocks = 3/CU resident.
  gemm_direct<1, 64><<<dim3(48, 16), 256, 0, stream>>>(xb, WqkvT, qkvb, TT, 3 * NE, NE);

  // tiled gathered attention; y (bf16) overlays xb
  attn4<<<dim3(TT / 16, NH), 256, 0, stream>>>(qkvb, nidx, xb, D);

  // out = y @ Wout, direct f32 write. 512 blocks = 2/CU resident.
  gemm_direct<0, 32><<<dim3(32, 16), 256, 0, stream>>>(xb, WoutT, out, TT, NE, NE);
}

// Round 8
// 45.845 us; speedup vs baseline: 7.4589x; 1.0134x over previous
//
#include <hip/hip_runtime.h>
#include <math.h>

#define NH 16
#define TT 1024
#define HD 64
#define NE 1024

typedef unsigned int u32;
typedef unsigned short u16;
typedef __bf16 bf16x8 __attribute__((ext_vector_type(8)));
typedef float f32x4 __attribute__((ext_vector_type(4)));

__device__ inline u16 f2bf(float f) {
  u32 u = __builtin_bit_cast(u32, f);
  u32 r = (u + 0x7fffu + ((u >> 16) & 1u)) >> 16;
  return (u16)r;
}
__device__ inline float bf2f(u16 h) {
  return __builtin_bit_cast(float, (u32)h << 16);
}
__device__ inline void gload16(const void* g, void* l) {
  __builtin_amdgcn_global_load_lds((const __attribute__((address_space(1))) void*)g,
                                   (__attribute__((address_space(3))) void*)l, 16, 0, 0);
}
__device__ inline u16 h16(uint4 v, int e) {
  u32 w = ((const u32*)&v)[e >> 1];
  return (e & 1) ? (u16)(w >> 16) : (u16)(w & 0xffffu);
}

// Fused prep: blocks [0,1024) convert x -> bf16; [1024,2048) transpose weights.
__global__ __launch_bounds__(256) void prep(const float* __restrict__ x,
                                            const float* __restrict__ Wqkv,
                                            const float* __restrict__ Wout,
                                            u16* __restrict__ xb,
                                            u16* __restrict__ WqkvT,
                                            u16* __restrict__ WoutT) {
  __shared__ float tile[64][65];
  const int tid = threadIdx.x;
  const int bx = blockIdx.x;
  if (bx < 1024) {
    int i = bx * 256 + tid;
    float4 f = ((const float4*)x)[i];
    ushort4 o = {f2bf(f.x), f2bf(f.y), f2bf(f.z), f2bf(f.w)};
    ((ushort4*)xb)[i] = o;
    return;
  }
  int b = bx - 1024;
  int nb = b & 63, kb = b >> 6;
  const float* W; u16* WT; int N, n0;
  if (nb < 48) { W = Wqkv; WT = WqkvT; N = 3 * NE; n0 = nb * 64; }
  else         { W = Wout; WT = WoutT; N = NE;     n0 = (nb - 48) * 64; }
  const int k0 = kb * 64;
#pragma unroll
  for (int it = 0; it < 16; ++it) {
    int idx = it * 256 + tid;
    int r = idx >> 6, c = idx & 63;
    tile[r][c] = W[(size_t)(k0 + r) * N + n0 + c];
  }
  __syncthreads();
#pragma unroll
  for (int it = 0; it < 16; ++it) {
    int idx = it * 256 + tid;
    int nn = idx >> 6, kk = idx & 63;
    WT[(size_t)(n0 + nn) * NE + k0 + kk] = f2bf(tile[kk][nn]);
  }
}

// Stage R rows x 64 k of bf16 into LDS, chunk-swizzled: slot(r,kg)=kg^(r&7).
template<int R>
__device__ __forceinline__ void stage_rows(const u16* __restrict__ G, int ldk,
                                           u16* L, int tid) {
#pragma unroll
  for (int it = 0; it < R / 32; ++it) {
    int idx = it * 256 + tid;
    int r = idx >> 3, kg = idx & 7;
    gload16(G + (size_t)r * ldk + ((kg ^ (r & 7)) << 3), L + (idx << 3));
  }
}

// bf16 MFMA GEMM: 64 x NT tile, BK=64, 4 waves (2x2), dbuf, swizzled LDS.
// 1D grid, XCD-aware: xcd = bid&7 owns col-tiles [xcd*CPX, (xcd+1)*CPX).
// MODE 0: f32 direct write. MODE 1: bf16 qkv scatter [which][h][t][d].
template<int MODE, int NT, int CPX>
__global__ __launch_bounds__(256) void gemm_direct(const u16* __restrict__ A,
                                                   const u16* __restrict__ Bt,
                                                   void* __restrict__ Cv,
                                                   int M, int N, int K) {
  __shared__ u16 As[2][64 * 64];
  __shared__ u16 Bs[2][NT * 64];
  const int tid = threadIdx.x;
  const int lane = tid & 63;
  const int wv = tid >> 6;
  const int wm = wv >> 1, wn = wv & 1;
  const int bid = blockIdx.x;
  const int xcd = bid & 7, loc = bid >> 3;
  const int row0 = (loc / CPX) * 64;
  const int col0 = (xcd * CPX + loc % CPX) * NT;
  const int nsteps = K >> 6;
  constexpr int NI = NT / 32;

  const u16* Ab = A + (size_t)row0 * K;
  const u16* Bb = Bt + (size_t)col0 * K;

  f32x4 acc[2][NI] = {};

  stage_rows<64>(Ab, K, As[0], tid);
  stage_rows<NT>(Bb, K, Bs[0], tid);
  __syncthreads();

  int buf = 0;
  for (int ks = 0; ks < nsteps; ++ks) {
    if (ks + 1 < nsteps) {
      stage_rows<64>(Ab + (ks + 1) * 64, K, As[buf ^ 1], tid);
      stage_rows<NT>(Bb + (ks + 1) * 64, K, Bs[buf ^ 1], tid);
    }
#pragma unroll
    for (int half = 0; half < 2; ++half) {
      const int kk = half * 32;
      bf16x8 af[2], bfr[NI];
#pragma unroll
      for (int mi = 0; mi < 2; ++mi) {
        int r = wm * 32 + mi * 16 + (lane & 15);
        int c = (kk >> 3) + (lane >> 4);
        af[mi] = *(const bf16x8*)&As[buf][(r * 8 + (c ^ (r & 7))) * 8];
      }
#pragma unroll
      for (int ni = 0; ni < NI; ++ni) {
        int r = wn * (NT / 2) + ni * 16 + (lane & 15);
        int c = (kk >> 3) + (lane >> 4);
        bfr[ni] = *(const bf16x8*)&Bs[buf][(r * 8 + (c ^ (r & 7))) * 8];
      }
#pragma unroll
      for (int mi = 0; mi < 2; ++mi)
#pragma unroll
        for (int ni = 0; ni < NI; ++ni)
          acc[mi][ni] = __builtin_amdgcn_mfma_f32_16x16x32_bf16(af[mi], bfr[ni], acc[mi][ni], 0, 0, 0);
    }
    __syncthreads();
    buf ^= 1;
  }

  const int rbase = row0 + wm * 32 + (lane >> 4) * 4;
  const int cbase = col0 + wn * (NT / 2) + (lane & 15);
#pragma unroll
  for (int mi = 0; mi < 2; ++mi) {
#pragma unroll
    for (int ni = 0; ni < NI; ++ni) {
      int n = cbase + ni * 16;
#pragma unroll
      for (int r = 0; r < 4; ++r) {
        int t = rbase + mi * 16 + r;
        float val = acc[mi][ni][r];
        if (MODE == 0) {
          ((float*)Cv)[(size_t)t * N + n] = val;
        } else {
          int which = n >> 10, h = (n & 1023) >> 6, d = n & 63;
          ((u16*)Cv)[(size_t)which * (NH * TT * HD) + (size_t)h * (TT * HD) +
                     (size_t)t * HD + d] = f2bf(val);
        }
      }
    }
  }
}

// Tiled gathered attention, MFMA QK^T + MFMA PV.
// 1D grid 1024, XCD-aware: xcd owns heads {2*xcd, 2*xcd+1} (K/V L2-local).
// <=128 superset columns (80 window, 16 landmarks, 32 prev/next dedup'd).
__global__ __launch_bounds__(256) void attn5(const u16* __restrict__ qkv,
                                             const int* __restrict__ nidx,
                                             u16* __restrict__ y, int D) {
  __shared__ __align__(16) u16 Qs[16 * 64];     // 2KB
  __shared__ __align__(16) u16 Ks[128 * 64];    // 16KB; S f32[16][132] overlays; P bf16 at +8448
  __shared__ __align__(16) u16 Vt[64 * 128];    // 16KB, octet-swizzled [d][k]
  __shared__ int pn_l[32];
  __shared__ int colj[128];
  __shared__ float rinv[16];
  float* S = (float*)Ks;
  u16* P = (u16*)((char*)Ks + 8448);

  const int tid = threadIdx.x;
  const int lane = tid & 63;
  const int wv = tid >> 6;
  const int bid = blockIdx.x;
  const int xcd = bid & 7, loc = bid >> 3;
  const int h = xcd * 2 + (loc & 1);
  const int t0 = (loc >> 1) * 16;

  const u16* qh = qkv + (size_t)h * TT * HD;
  const u16* kh = qkv + (size_t)NH * TT * HD + (size_t)h * TT * HD;
  const u16* vh = qkv + 2 * (size_t)NH * TT * HD + (size_t)h * TT * HD;

  if (tid < 32) pn_l[tid] = nidx[((size_t)h * TT + t0 + (tid >> 1)) * D + (tid & 1)];
  // Q staging doesn't depend on colj/pn_l: issue now
  if (tid < 128) {
    int row = tid >> 3, slot = tid & 7, ch = slot ^ (row & 7);
    gload16(qh + (size_t)(t0 + row) * HD + ch * 8, Qs + tid * 8);
  }
  __syncthreads();

  if (tid < 128) {
    int c = tid, j;
    if (c < 80) {
      j = t0 - 64 + c;
      if (j < 0) j = -1;
    } else if (c < 96) {
      j = (c - 80) * 64;
      if (j >= t0 - 64) j = -1;
    } else {
      int s = c - 96;
      j = pn_l[s];
      bool keep = (j < t0 - 64) && ((j & 63) != 0);
      if (keep)
        for (int s2 = 0; s2 < s; ++s2)
          if (pn_l[s2] == j) { keep = false; break; }
      if (!keep) j = -1;
    }
    colj[c] = j;
  }
  __syncthreads();

  // K -> LDS (chunk-swizzled gather); V -> registers (4 consecutive cols x d-octet)
#pragma unroll
  for (int it = 0; it < 4; ++it) {
    int idx = it * 256 + tid;
    int col = idx >> 3, slot = idx & 7, ch = slot ^ (col & 7);
    int j = colj[col]; if (j < 0) j = 0;
    gload16(kh + (size_t)j * HD + ch * 8, Ks + idx * 8);
  }
  const int d0 = (tid & 7) * 8;
  const int cq = tid >> 3;          // col-quad 0..31 -> cols cq*4..+3
  uint4 vreg[4];
#pragma unroll
  for (int it = 0; it < 4; ++it) {
    int col = cq * 4 + it;
    int j = colj[col]; if (j < 0) j = 0;
    vreg[it] = *(const uint4*)(vh + (size_t)j * HD + d0);
  }
  __syncthreads();

  // QK^T: wave wv owns col-tiles 2wv, 2wv+1
  f32x4 sc[2] = {};
  bf16x8 af[2];
#pragma unroll
  for (int half = 0; half < 2; ++half) {
    int row = lane & 15;
    int chunk = 4 * half + (lane >> 4);
    af[half] = *(const bf16x8*)&Qs[(row * 8 + (chunk ^ (row & 7))) * 8];
  }
#pragma unroll
  for (int p = 0; p < 2; ++p) {
    int col = 16 * (2 * wv + p) + (lane & 15);
#pragma unroll
    for (int half = 0; half < 2; ++half) {
      int chunk = 4 * half + (lane >> 4);
      bf16x8 bfv = *(const bf16x8*)&Ks[(col * 8 + (chunk ^ (col & 7))) * 8];
      sc[p] = __builtin_amdgcn_mfma_f32_16x16x32_bf16(af[half], bfv, sc[p], 0, 0, 0);
    }
  }
  __syncthreads();   // done reading Ks; S may overlay

  // mask + S write
#pragma unroll
  for (int p = 0; p < 2; ++p) {
    int col = 16 * (2 * wv + p) + (lane & 15);
    int j = colj[col];
#pragma unroll
    for (int r = 0; r < 4; ++r) {
      int row = (lane >> 4) * 4 + r;
      int i = t0 + row;
      int p0 = pn_l[2 * row], p1 = pn_l[2 * row + 1];
      bool m;
      if (col < 80)      m = (j >= 0) && (j <= i) &&
                             ((i - j) <= 64 || (j & 63) == 0 || j == p0 || j == p1);
      else if (col < 96) m = (j >= 0);
      else               m = (j >= 0) && (j == p0 || j == p1);
      S[row * 132 + col] = m ? ((float)sc[p][r]) * 0.125f : -1e30f;
    }
  }
  __syncthreads();

  // softmax (row team = 16 lanes, 8 contiguous cols each) + P(bf16) write
  {
    int row = tid >> 4, q = tid & 15;
    float v[8];
    float mx = -3e38f;
#pragma unroll
    for (int e = 0; e < 8; ++e) {
      v[e] = S[row * 132 + 8 * q + e];
      mx = fmaxf(mx, v[e]);
    }
#pragma unroll
    for (int off = 1; off < 16; off <<= 1) mx = fmaxf(mx, __shfl_xor(mx, off, 64));
    float sum = 0.f;
#pragma unroll
    for (int e = 0; e < 8; ++e) {
      v[e] = __expf(v[e] - mx);
      sum += v[e];
    }
#pragma unroll
    for (int off = 1; off < 16; off <<= 1) sum += __shfl_xor(sum, off, 64);
    if (q == 0) rinv[row] = 1.0f / sum;
    u32 w0 = (u32)f2bf(v[0]) | ((u32)f2bf(v[1]) << 16);
    u32 w1 = (u32)f2bf(v[2]) | ((u32)f2bf(v[3]) << 16);
    u32 w2 = (u32)f2bf(v[4]) | ((u32)f2bf(v[5]) << 16);
    u32 w3 = (u32)f2bf(v[6]) | ((u32)f2bf(v[7]) << 16);
    uint4 pk = {w0, w1, w2, w3};
    *(uint4*)&P[row * 128 + ((q ^ (row & 7)) << 3)] = pk;
  }

  // Vt transpose-write, b64 along k: Vt[d] octet o holds cols [o^(d&7)^((d>>3)&7)]*8..+8
#pragma unroll
  for (int e = 0; e < 8; ++e) {
    int d = d0 + e;
    u32 lo = (u32)h16(vreg[0], e) | ((u32)h16(vreg[1], e) << 16);
    u32 hi = (u32)h16(vreg[2], e) | ((u32)h16(vreg[3], e) << 16);
    int oswz = (cq >> 1) ^ (d & 7) ^ ((d >> 3) & 7);
    uint2 pk2 = {lo, hi};
    *(uint2*)&Vt[d * 128 + oswz * 8 + (cq & 1) * 4] = pk2;
  }
  __syncthreads();

  // PV: wave wv owns d-tile wv. out 16x16 per wave.
  f32x4 oacc = {};
#pragma unroll
  for (int ks2 = 0; ks2 < 4; ++ks2) {
    int rowp = lane & 15;
    int chp = ks2 * 4 + (lane >> 4);
    bf16x8 pa = *(const bf16x8*)&P[rowp * 128 + ((chp ^ (rowp & 7)) << 3)];
    int dd = wv * 16 + (lane & 15);
    int swz = chp ^ (dd & 7) ^ ((dd >> 3) & 7);
    bf16x8 vb = *(const bf16x8*)&Vt[dd * 128 + swz * 8];
    oacc = __builtin_amdgcn_mfma_f32_16x16x32_bf16(pa, vb, oacc, 0, 0, 0);
  }
  {
    int dd = wv * 16 + (lane & 15);
#pragma unroll
    for (int r = 0; r < 4; ++r) {
      int row = (lane >> 4) * 4 + r;
      y[(size_t)(t0 + row) * NE + h * HD + dd] = f2bf(oacc[r] * rinv[row]);
    }
  }
}

extern "C" void kernel_launch(void* const* d_in, const int* in_sizes, int n_in,
                              void* d_out, int out_size, void* d_ws, size_t ws_size,
                              hipStream_t stream) {
  const float* x    = (const float*)d_in[0];
  const float* Wqkv = (const float*)d_in[1];
  const float* Wout = (const float*)d_in[2];
  const int*   nidx = (const int*)d_in[3];
  float* out = (float*)d_out;

  u16* ws16  = (u16*)d_ws;
  u16* xb    = ws16;                 // 2MB; reused as y after gemm1
  u16* WqkvT = ws16 + 1048576;       // 6MB
  u16* WoutT = ws16 + 4194304;       // 2MB
  u16* qkvb  = ws16 + 5242880;       // 6MB

  const int D = in_sizes[3] / (NH * TT);   // 83

  prep<<<2048, 256, 0, stream>>>(x, Wqkv, Wout, xb, WqkvT, WoutT);

  // qkv = x @ Wqkv, bf16 scatter epilogue. 768 blocks, XCD-local col slices.
  gemm_direct<1, 64, 6><<<768, 256, 0, stream>>>(xb, WqkvT, qkvb, TT, 3 * NE, NE);

  // tiled gathered attention; y (bf16) overlays xb. XCD-local heads.
  attn5<<<1024, 256, 0, stream>>>(qkvb, nidx, xb, D);

  // out = y @ Wout, direct f32 write. 512 blocks, XCD-local col slices.
  gemm_direct<0, 32, 4><<<512, 256, 0, stream>>>(xb, WoutT, out, TT, NE, NE);
}

// Round 9
// 45.786 us; speedup vs baseline: 7.4685x; 1.0013x over previous
//
#include <hip/hip_runtime.h>
#include <math.h>

#define NH 16
#define TT 1024
#define HD 64
#define NE 1024

typedef unsigned int u32;
typedef unsigned short u16;
typedef __bf16 bf16x8 __attribute__((ext_vector_type(8)));
typedef float f32x4 __attribute__((ext_vector_type(4)));

__device__ inline u16 f2bf(float f) {
  u32 u = __builtin_bit_cast(u32, f);
  u32 r = (u + 0x7fffu + ((u >> 16) & 1u)) >> 16;
  return (u16)r;
}
__device__ inline float bf2f(u16 h) {
  return __builtin_bit_cast(float, (u32)h << 16);
}
__device__ inline void gload16(const void* g, void* l) {
  __builtin_amdgcn_global_load_lds((const __attribute__((address_space(1))) void*)g,
                                   (__attribute__((address_space(3))) void*)l, 16, 0, 0);
}
__device__ inline u16 h16(uint4 v, int e) {
  u32 w = ((const u32*)&v)[e >> 1];
  return (e & 1) ? (u16)(w >> 16) : (u16)(w & 0xffffu);
}
// raw workgroup barrier with compiler-level memory fence (no vmcnt/lgkmcnt drain)
__device__ inline void block_bar() {
  asm volatile("" ::: "memory");
  __builtin_amdgcn_s_barrier();
  asm volatile("" ::: "memory");
}

// Fused prep: blocks [0,1024) convert x -> bf16; [1024,2048) transpose weights.
__global__ __launch_bounds__(256) void prep(const float* __restrict__ x,
                                            const float* __restrict__ Wqkv,
                                            const float* __restrict__ Wout,
                                            u16* __restrict__ xb,
                                            u16* __restrict__ WqkvT,
                                            u16* __restrict__ WoutT) {
  __shared__ float tile[64][65];
  const int tid = threadIdx.x;
  const int bx = blockIdx.x;
  if (bx < 1024) {
    int i = bx * 256 + tid;
    float4 f = ((const float4*)x)[i];
    ushort4 o = {f2bf(f.x), f2bf(f.y), f2bf(f.z), f2bf(f.w)};
    ((ushort4*)xb)[i] = o;
    return;
  }
  int b = bx - 1024;
  int nb = b & 63, kb = b >> 6;
  const float* W; u16* WT; int N, n0;
  if (nb < 48) { W = Wqkv; WT = WqkvT; N = 3 * NE; n0 = nb * 64; }
  else         { W = Wout; WT = WoutT; N = NE;     n0 = (nb - 48) * 64; }
  const int k0 = kb * 64;
#pragma unroll
  for (int it = 0; it < 16; ++it) {
    int idx = it * 256 + tid;
    int r = idx >> 6, c = idx & 63;
    tile[r][c] = W[(size_t)(k0 + r) * N + n0 + c];
  }
  __syncthreads();
#pragma unroll
  for (int it = 0; it < 16; ++it) {
    int idx = it * 256 + tid;
    int nn = idx >> 6, kk = idx & 63;
    WT[(size_t)(n0 + nn) * NE + k0 + kk] = f2bf(tile[kk][nn]);
  }
}

// Stage R rows x 64 k of bf16 into LDS, chunk-swizzled: slot(r,kg)=kg^(r&7).
template<int R>
__device__ __forceinline__ void stage_rows(const u16* __restrict__ G, int ldk,
                                           u16* L, int tid) {
#pragma unroll
  for (int it = 0; it < R / 32; ++it) {
    int idx = it * 256 + tid;
    int r = idx >> 3, kg = idx & 7;
    gload16(G + (size_t)r * ldk + ((kg ^ (r & 7)) << 3), L + (idx << 3));
  }
}

// bf16 MFMA GEMM: 64 x NT tile, BK=64, 4 waves (2x2), 2-deep prefetch with
// COUNTED vmcnt (never drains to 0 mid-loop) + raw barriers. Swizzled LDS.
// 1D grid, XCD-aware: xcd = bid&7 owns col-tiles [xcd*CPX, (xcd+1)*CPX).
// MODE 0: f32 direct write. MODE 1: bf16 qkv scatter [which][h][t][d].
template<int MODE, int NT, int CPX>
__global__ __launch_bounds__(256) void gemm_direct(const u16* __restrict__ A,
                                                   const u16* __restrict__ Bt,
                                                   void* __restrict__ Cv,
                                                   int M, int N, int K) {
  __shared__ u16 As[2][64 * 64];
  __shared__ u16 Bs[2][NT * 64];
  const int tid = threadIdx.x;
  const int lane = tid & 63;
  const int wv = tid >> 6;
  const int wm = wv >> 1, wn = wv & 1;
  const int bid = blockIdx.x;
  const int xcd = bid & 7, loc = bid >> 3;
  const int row0 = (loc / CPX) * 64;
  const int col0 = (xcd * CPX + loc % CPX) * NT;
  const int nsteps = K >> 6;
  constexpr int NI = NT / 32;
  constexpr int SPW = 2 + NI;   // staging instructions per thread per K-step

  const u16* Ab = A + (size_t)row0 * K;
  const u16* Bb = Bt + (size_t)col0 * K;

  f32x4 acc[2][NI] = {};

  // 2-deep prefetch prologue
  stage_rows<64>(Ab, K, As[0], tid);
  stage_rows<NT>(Bb, K, Bs[0], tid);
  stage_rows<64>(Ab + 64, K, As[1], tid);
  stage_rows<NT>(Bb + 64, K, Bs[1], tid);

  for (int ks = 0; ks < nsteps; ++ks) {
    // wait for buf[ks]'s loads only; keep buf[ks+1]'s SPW loads in flight
    if (ks < nsteps - 1) {
      if constexpr (SPW == 4) asm volatile("s_waitcnt vmcnt(4)" ::: "memory");
      else                    asm volatile("s_waitcnt vmcnt(3)" ::: "memory");
    } else {
      asm volatile("s_waitcnt vmcnt(0)" ::: "memory");
    }
    __builtin_amdgcn_sched_barrier(0);
    block_bar();                      // buf[ks] globally ready

    const int buf = ks & 1;
#pragma unroll
    for (int half = 0; half < 2; ++half) {
      const int kk = half * 32;
      bf16x8 af[2], bfr[NI];
#pragma unroll
      for (int mi = 0; mi < 2; ++mi) {
        int r = wm * 32 + mi * 16 + (lane & 15);
        int c = (kk >> 3) + (lane >> 4);
        af[mi] = *(const bf16x8*)&As[buf][(r * 8 + (c ^ (r & 7))) * 8];
      }
#pragma unroll
      for (int ni = 0; ni < NI; ++ni) {
        int r = wn * (NT / 2) + ni * 16 + (lane & 15);
        int c = (kk >> 3) + (lane >> 4);
        bfr[ni] = *(const bf16x8*)&Bs[buf][(r * 8 + (c ^ (r & 7))) * 8];
      }
#pragma unroll
      for (int mi = 0; mi < 2; ++mi)
#pragma unroll
        for (int ni = 0; ni < NI; ++ni)
          acc[mi][ni] = __builtin_amdgcn_mfma_f32_16x16x32_bf16(af[mi], bfr[ni], acc[mi][ni], 0, 0, 0);
    }

    block_bar();                      // all threads done reading buf[ks]
    if (ks + 2 < nsteps) {            // safe to overwrite buf[ks] now
      stage_rows<64>(Ab + (size_t)(ks + 2) * 64, K, As[buf], tid);
      stage_rows<NT>(Bb + (size_t)(ks + 2) * 64, K, Bs[buf], tid);
    }
  }

  const int rbase = row0 + wm * 32 + (lane >> 4) * 4;
  const int cbase = col0 + wn * (NT / 2) + (lane & 15);
#pragma unroll
  for (int mi = 0; mi < 2; ++mi) {
#pragma unroll
    for (int ni = 0; ni < NI; ++ni) {
      int n = cbase + ni * 16;
#pragma unroll
      for (int r = 0; r < 4; ++r) {
        int t = rbase + mi * 16 + r;
        float val = acc[mi][ni][r];
        if (MODE == 0) {
          ((float*)Cv)[(size_t)t * N + n] = val;
        } else {
          int which = n >> 10, h = (n & 1023) >> 6, d = n & 63;
          ((u16*)Cv)[(size_t)which * (NH * TT * HD) + (size_t)h * (TT * HD) +
                     (size_t)t * HD + d] = f2bf(val);
        }
      }
    }
  }
}

// Tiled gathered attention, MFMA QK^T + MFMA PV.
// 1D grid 1024, XCD-aware: xcd owns heads {2*xcd, 2*xcd+1} (K/V L2-local).
// <=128 superset columns (80 window, 16 landmarks, 32 prev/next dedup'd).
__global__ __launch_bounds__(256) void attn5(const u16* __restrict__ qkv,
                                             const int* __restrict__ nidx,
                                             u16* __restrict__ y, int D) {
  __shared__ __align__(16) u16 Qs[16 * 64];     // 2KB
  __shared__ __align__(16) u16 Ks[128 * 64];    // 16KB; S f32[16][132] overlays; P bf16 at +8448
  __shared__ __align__(16) u16 Vt[64 * 128];    // 16KB, octet-swizzled [d][k]
  __shared__ int pn_l[32];
  __shared__ int colj[128];
  __shared__ float rinv[16];
  float* S = (float*)Ks;
  u16* P = (u16*)((char*)Ks + 8448);

  const int tid = threadIdx.x;
  const int lane = tid & 63;
  const int wv = tid >> 6;
  const int bid = blockIdx.x;
  const int xcd = bid & 7, loc = bid >> 3;
  const int h = xcd * 2 + (loc & 1);
  const int t0 = (loc >> 1) * 16;

  const u16* qh = qkv + (size_t)h * TT * HD;
  const u16* kh = qkv + (size_t)NH * TT * HD + (size_t)h * TT * HD;
  const u16* vh = qkv + 2 * (size_t)NH * TT * HD + (size_t)h * TT * HD;

  if (tid < 32) pn_l[tid] = nidx[((size_t)h * TT + t0 + (tid >> 1)) * D + (tid & 1)];
  // Q staging doesn't depend on colj/pn_l: issue now
  if (tid < 128) {
    int row = tid >> 3, slot = tid & 7, ch = slot ^ (row & 7);
    gload16(qh + (size_t)(t0 + row) * HD + ch * 8, Qs + tid * 8);
  }
  __syncthreads();

  if (tid < 128) {
    int c = tid, j;
    if (c < 80) {
      j = t0 - 64 + c;
      if (j < 0) j = -1;
    } else if (c < 96) {
      j = (c - 80) * 64;
      if (j >= t0 - 64) j = -1;
    } else {
      int s = c - 96;
      j = pn_l[s];
      bool keep = (j < t0 - 64) && ((j & 63) != 0);
      if (keep)
        for (int s2 = 0; s2 < s; ++s2)
          if (pn_l[s2] == j) { keep = false; break; }
      if (!keep) j = -1;
    }
    colj[c] = j;
  }
  __syncthreads();

  // K -> LDS (chunk-swizzled gather); V -> registers (4 consecutive cols x d-octet)
#pragma unroll
  for (int it = 0; it < 4; ++it) {
    int idx = it * 256 + tid;
    int col = idx >> 3, slot = idx & 7, ch = slot ^ (col & 7);
    int j = colj[col]; if (j < 0) j = 0;
    gload16(kh + (size_t)j * HD + ch * 8, Ks + idx * 8);
  }
  const int d0 = (tid & 7) * 8;
  const int cq = tid >> 3;          // col-quad 0..31 -> cols cq*4..+3
  uint4 vreg[4];
#pragma unroll
  for (int it = 0; it < 4; ++it) {
    int col = cq * 4 + it;
    int j = colj[col]; if (j < 0) j = 0;
    vreg[it] = *(const uint4*)(vh + (size_t)j * HD + d0);
  }
  __syncthreads();

  // QK^T: wave wv owns col-tiles 2wv, 2wv+1
  f32x4 sc[2] = {};
  bf16x8 af[2];
#pragma unroll
  for (int half = 0; half < 2; ++half) {
    int row = lane & 15;
    int chunk = 4 * half + (lane >> 4);
    af[half] = *(const bf16x8*)&Qs[(row * 8 + (chunk ^ (row & 7))) * 8];
  }
#pragma unroll
  for (int p = 0; p < 2; ++p) {
    int col = 16 * (2 * wv + p) + (lane & 15);
#pragma unroll
    for (int half = 0; half < 2; ++half) {
      int chunk = 4 * half + (lane >> 4);
      bf16x8 bfv = *(const bf16x8*)&Ks[(col * 8 + (chunk ^ (col & 7))) * 8];
      sc[p] = __builtin_amdgcn_mfma_f32_16x16x32_bf16(af[half], bfv, sc[p], 0, 0, 0);
    }
  }
  __syncthreads();   // done reading Ks; S may overlay

  // mask + S write
#pragma unroll
  for (int p = 0; p < 2; ++p) {
    int col = 16 * (2 * wv + p) + (lane & 15);
    int j = colj[col];
#pragma unroll
    for (int r = 0; r < 4; ++r) {
      int row = (lane >> 4) * 4 + r;
      int i = t0 + row;
      int p0 = pn_l[2 * row], p1 = pn_l[2 * row + 1];
      bool m;
      if (col < 80)      m = (j >= 0) && (j <= i) &&
                             ((i - j) <= 64 || (j & 63) == 0 || j == p0 || j == p1);
      else if (col < 96) m = (j >= 0);
      else               m = (j >= 0) && (j == p0 || j == p1);
      S[row * 132 + col] = m ? ((float)sc[p][r]) * 0.125f : -1e30f;
    }
  }
  __syncthreads();

  // softmax (row team = 16 lanes, 8 contiguous cols each) + P(bf16) write
  {
    int row = tid >> 4, q = tid & 15;
    float v[8];
    float mx = -3e38f;
#pragma unroll
    for (int e = 0; e < 8; ++e) {
      v[e] = S[row * 132 + 8 * q + e];
      mx = fmaxf(mx, v[e]);
    }
#pragma unroll
    for (int off = 1; off < 16; off <<= 1) mx = fmaxf(mx, __shfl_xor(mx, off, 64));
    float sum = 0.f;
#pragma unroll
    for (int e = 0; e < 8; ++e) {
      v[e] = __expf(v[e] - mx);
      sum += v[e];
    }
#pragma unroll
    for (int off = 1; off < 16; off <<= 1) sum += __shfl_xor(sum, off, 64);
    if (q == 0) rinv[row] = 1.0f / sum;
    u32 w0 = (u32)f2bf(v[0]) | ((u32)f2bf(v[1]) << 16);
    u32 w1 = (u32)f2bf(v[2]) | ((u32)f2bf(v[3]) << 16);
    u32 w2 = (u32)f2bf(v[4]) | ((u32)f2bf(v[5]) << 16);
    u32 w3 = (u32)f2bf(v[6]) | ((u32)f2bf(v[7]) << 16);
    uint4 pk = {w0, w1, w2, w3};
    *(uint4*)&P[row * 128 + ((q ^ (row & 7)) << 3)] = pk;
  }

  // Vt transpose-write, b64 along k: Vt[d] octet o holds cols [o^(d&7)^((d>>3)&7)]*8..+8
#pragma unroll
  for (int e = 0; e < 8; ++e) {
    int d = d0 + e;
    u32 lo = (u32)h16(vreg[0], e) | ((u32)h16(vreg[1], e) << 16);
    u32 hi = (u32)h16(vreg[2], e) | ((u32)h16(vreg[3], e) << 16);
    int oswz = (cq >> 1) ^ (d & 7) ^ ((d >> 3) & 7);
    uint2 pk2 = {lo, hi};
    *(uint2*)&Vt[d * 128 + oswz * 8 + (cq & 1) * 4] = pk2;
  }
  __syncthreads();

  // PV: wave wv owns d-tile wv. out 16x16 per wave.
  f32x4 oacc = {};
#pragma unroll
  for (int ks2 = 0; ks2 < 4; ++ks2) {
    int rowp = lane & 15;
    int chp = ks2 * 4 + (lane >> 4);
    bf16x8 pa = *(const bf16x8*)&P[rowp * 128 + ((chp ^ (rowp & 7)) << 3)];
    int dd = wv * 16 + (lane & 15);
    int swz = chp ^ (dd & 7) ^ ((dd >> 3) & 7);
    bf16x8 vb = *(const bf16x8*)&Vt[dd * 128 + swz * 8];
    oacc = __builtin_amdgcn_mfma_f32_16x16x32_bf16(pa, vb, oacc, 0, 0, 0);
  }
  {
    int dd = wv * 16 + (lane & 15);
#pragma unroll
    for (int r = 0; r < 4; ++r) {
      int row = (lane >> 4) * 4 + r;
      y[(size_t)(t0 + row) * NE + h * HD + dd] = f2bf(oacc[r] * rinv[row]);
    }
  }
}

extern "C" void kernel_launch(void* const* d_in, const int* in_sizes, int n_in,
                              void* d_out, int out_size, void* d_ws, size_t ws_size,
                              hipStream_t stream) {
  const float* x    = (const float*)d_in[0];
  const float* Wqkv = (const float*)d_in[1];
  const float* Wout = (const float*)d_in[2];
  const int*   nidx = (const int*)d_in[3];
  float* out = (float*)d_out;

  u16* ws16  = (u16*)d_ws;
  u16* xb    = ws16;                 // 2MB; reused as y after gemm1
  u16* WqkvT = ws16 + 1048576;       // 6MB
  u16* WoutT = ws16 + 4194304;       // 2MB
  u16* qkvb  = ws16 + 5242880;       // 6MB

  const int D = in_sizes[3] / (NH * TT);   // 83

  prep<<<2048, 256, 0, stream>>>(x, Wqkv, Wout, xb, WqkvT, WoutT);

  // qkv = x @ Wqkv, bf16 scatter epilogue. 768 blocks, XCD-local col slices.
  gemm_direct<1, 64, 6><<<768, 256, 0, stream>>>(xb, WqkvT, qkvb, TT, 3 * NE, NE);

  // tiled gathered attention; y (bf16) overlays xb. XCD-local heads.
  attn5<<<1024, 256, 0, stream>>>(qkvb, nidx, xb, D);

  // out = y @ Wout, direct f32 write. 512 blocks, XCD-local col slices.
  gemm_direct<0, 32, 4><<<512, 256, 0, stream>>>(xb, WoutT, out, TT, NE, NE);
}